// Round 2
// baseline (54250.745 us; speedup 1.0000x reference)
//
#include <hip/hip_runtime.h>

typedef unsigned short u16;
typedef unsigned int u32;

namespace {
constexpr int kH    = 512;
constexpr int kS    = 256;
constexpr int kT    = 512;
constexpr int kR    = 128;
constexpr int kB    = 128;
constexpr int kEMB  = 300;
constexpr int kTAGE = 20;
constexpr int kTRE  = 20;
constexpr int kNT   = 100;
}

__device__ __forceinline__ float bf(u16 v){ return __uint_as_float(((u32)v)<<16); }
__device__ __forceinline__ u16 f2bf(float f){
  u32 u = __float_as_uint(f);
  return (u16)((u + 0x7fffu + ((u>>16)&1u)) >> 16);
}
__device__ __forceinline__ float sigm(float x){ return 1.f/(1.f+__expf(-x)); }
__device__ __forceinline__ float tanha(float x){ return 2.f/(1.f+__expf(-2.f*x)) - 1.f; }
__device__ __forceinline__ float wred(float v){
  #pragma unroll
  for (int off=32; off>0; off>>=1) v += __shfl_xor(v, off, 64);
  return v;
}

// ---------------- word LSTM step: X = [emb | tag_emb] gathered, K=320 ----------------
__global__ __launch_bounds__(256) void k_word_step(
    const int* __restrict__ word_idx, const int* __restrict__ tag_idx,
    const float* __restrict__ emb, const float* __restrict__ tag_emb,
    const float* __restrict__ Wih, const float* __restrict__ Whh,
    const float* __restrict__ bias,
    float* __restrict__ word_h, float* __restrict__ c_st, int s)
{
  const int wid  = blockIdx.x*4 + (threadIdx.x>>6);
  const int lane = threadIdx.x & 63;
  const int j  = wid & 511;
  const int mg = wid >> 9;   // 0..31

  float x[4][5];
  float h[4][8];
  #pragma unroll
  for (int mi=0; mi<4; ++mi){
    const int b  = mg*4+mi;
    const int wi = word_idx[b*kS+s];
    const int ti = tag_idx[b*kS+s];
    const float* er = emb + (size_t)wi*kEMB;
    const float* tr = tag_emb + (size_t)ti*kTAGE;
    #pragma unroll
    for (int i=0;i<5;++i){
      const int k = i*64+lane;
      x[mi][i] = (k < kEMB) ? er[k] : tr[k-kEMB];
    }
  }
  if (s > 0){
    #pragma unroll
    for (int mi=0;mi<4;++mi){
      const float* hp = word_h + ((size_t)(mg*4+mi)*kS + (s-1))*kH;
      #pragma unroll
      for (int i=0;i<8;++i) h[mi][i] = hp[i*64+lane];
    }
  }

  float acc[4][4];
  #pragma unroll
  for (int g=0;g<4;++g)
    #pragma unroll
    for (int mi=0;mi<4;++mi) acc[g][mi] = 0.f;

  #pragma unroll
  for (int g=0;g<4;++g){
    const float* wx = Wih + (size_t)(g*kH+j)*(kEMB+kTAGE);
    #pragma unroll
    for (int i=0;i<5;++i){
      const float wv = wx[i*64+lane];
      #pragma unroll
      for (int mi=0;mi<4;++mi) acc[g][mi] += x[mi][i]*wv;
    }
  }
  if (s > 0){
    #pragma unroll
    for (int g=0;g<4;++g){
      const float* wh = Whh + (size_t)(g*kH+j)*kH;
      #pragma unroll
      for (int i=0;i<8;++i){
        const float wv = wh[i*64+lane];
        #pragma unroll
        for (int mi=0;mi<4;++mi) acc[g][mi] += h[mi][i]*wv;
      }
    }
  }
  #pragma unroll
  for (int g=0;g<4;++g)
    #pragma unroll
    for (int mi=0;mi<4;++mi) acc[g][mi] = wred(acc[g][mi]);

  if (lane == 0){
    const float bi = bias[0*kH+j];
    const float bfv = bias[1*kH+j];
    const float bg = bias[2*kH+j];
    const float bo = bias[3*kH+j];
    #pragma unroll
    for (int mi=0;mi<4;++mi){
      const int b = mg*4+mi;
      const float iv = sigm(acc[0][mi]+bi);
      const float fv = sigm(acc[1][mi]+bfv);
      const float gv = tanha(acc[2][mi]+bg);
      const float ov = sigm(acc[3][mi]+bo);
      const float cold = (s>0) ? c_st[b*kH+j] : 0.f;
      const float c = fv*cold + iv*gv;
      c_st[b*kH+j] = c;
      word_h[((size_t)b*kS+s)*kH + j] = ov*tanha(c);
    }
  }
}

// ---------------- transition LSTM step: X = tr_emb gathered, K=20 ----------------
__global__ __launch_bounds__(256) void k_tr_step(
    const int* __restrict__ tr_idx, const float* __restrict__ tr_emb,
    const float* __restrict__ Wih, const float* __restrict__ Whh,
    const float* __restrict__ bias,
    const float* __restrict__ h_prev, float* __restrict__ h_next,
    float* __restrict__ c_st, int s)
{
  const int wid  = blockIdx.x*4 + (threadIdx.x>>6);
  const int lane = threadIdx.x & 63;
  const int j  = wid & 511;
  const int mg = wid >> 9;

  float x[4];
  float h[4][8];
  #pragma unroll
  for (int mi=0;mi<4;++mi){
    const int b = mg*4+mi;
    const int ti = tr_idx[b*kT+s];
    x[mi] = (lane < kTRE) ? tr_emb[(size_t)ti*kTRE + lane] : 0.f;
  }
  if (s > 0){
    #pragma unroll
    for (int mi=0;mi<4;++mi){
      const float* hp = h_prev + (size_t)(mg*4+mi)*kH;
      #pragma unroll
      for (int i=0;i<8;++i) h[mi][i] = hp[i*64+lane];
    }
  }

  float acc[4][4];
  #pragma unroll
  for (int g=0;g<4;++g)
    #pragma unroll
    for (int mi=0;mi<4;++mi) acc[g][mi] = 0.f;

  #pragma unroll
  for (int g=0;g<4;++g){
    const float wv = (lane < kTRE) ? Wih[(size_t)(g*kH+j)*kTRE + lane] : 0.f;
    #pragma unroll
    for (int mi=0;mi<4;++mi) acc[g][mi] += x[mi]*wv;
  }
  if (s > 0){
    #pragma unroll
    for (int g=0;g<4;++g){
      const float* wh = Whh + (size_t)(g*kH+j)*kH;
      #pragma unroll
      for (int i=0;i<8;++i){
        const float wv = wh[i*64+lane];
        #pragma unroll
        for (int mi=0;mi<4;++mi) acc[g][mi] += h[mi][i]*wv;
      }
    }
  }
  #pragma unroll
  for (int g=0;g<4;++g)
    #pragma unroll
    for (int mi=0;mi<4;++mi) acc[g][mi] = wred(acc[g][mi]);

  if (lane == 0){
    const float bi = bias[0*kH+j];
    const float bfv = bias[1*kH+j];
    const float bg = bias[2*kH+j];
    const float bo = bias[3*kH+j];
    #pragma unroll
    for (int mi=0;mi<4;++mi){
      const int b = mg*4+mi;
      const float iv = sigm(acc[0][mi]+bi);
      const float fv = sigm(acc[1][mi]+bfv);
      const float gv = tanha(acc[2][mi]+bg);
      const float ov = sigm(acc[3][mi]+bo);
      const float cold = (s>0) ? c_st[b*kH+j] : 0.f;
      const float c = fv*cold + iv*gv;
      c_st[b*kH+j] = c;
      h_next[(size_t)b*kH+j] = ov*tanha(c);
    }
  }
}

// ---------------- constituent LSTM step: X = red rows (f32), K=512 ----------------
__global__ __launch_bounds__(256) void k_con_step(
    const float* __restrict__ red,
    const float* __restrict__ Wih, const float* __restrict__ Whh,
    const float* __restrict__ bias,
    const float* __restrict__ h_prev, float* __restrict__ h_next,
    float* __restrict__ c_st, int s)
{
  const int wid  = blockIdx.x*4 + (threadIdx.x>>6);
  const int lane = threadIdx.x & 63;
  const int j  = wid & 511;
  const int mg = wid >> 9;

  float x[4][8];
  float h[4][8];
  #pragma unroll
  for (int mi=0;mi<4;++mi){
    const int b = mg*4+mi;
    const float* xr = red + ((size_t)b*kR + s)*kH;
    #pragma unroll
    for (int i=0;i<8;++i) x[mi][i] = xr[i*64+lane];
  }
  if (s > 0){
    #pragma unroll
    for (int mi=0;mi<4;++mi){
      const float* hp = h_prev + (size_t)(mg*4+mi)*kH;
      #pragma unroll
      for (int i=0;i<8;++i) h[mi][i] = hp[i*64+lane];
    }
  }

  float acc[4][4];
  #pragma unroll
  for (int g=0;g<4;++g)
    #pragma unroll
    for (int mi=0;mi<4;++mi) acc[g][mi] = 0.f;

  #pragma unroll
  for (int g=0;g<4;++g){
    const float* wx = Wih + (size_t)(g*kH+j)*kH;
    #pragma unroll
    for (int i=0;i<8;++i){
      const float wv = wx[i*64+lane];
      #pragma unroll
      for (int mi=0;mi<4;++mi) acc[g][mi] += x[mi][i]*wv;
    }
  }
  if (s > 0){
    #pragma unroll
    for (int g=0;g<4;++g){
      const float* wh = Whh + (size_t)(g*kH+j)*kH;
      #pragma unroll
      for (int i=0;i<8;++i){
        const float wv = wh[i*64+lane];
        #pragma unroll
        for (int mi=0;mi<4;++mi) acc[g][mi] += h[mi][i]*wv;
      }
    }
  }
  #pragma unroll
  for (int g=0;g<4;++g)
    #pragma unroll
    for (int mi=0;mi<4;++mi) acc[g][mi] = wred(acc[g][mi]);

  if (lane == 0){
    const float bi = bias[0*kH+j];
    const float bfv = bias[1*kH+j];
    const float bg = bias[2*kH+j];
    const float bo = bias[3*kH+j];
    #pragma unroll
    for (int mi=0;mi<4;++mi){
      const int b = mg*4+mi;
      const float iv = sigm(acc[0][mi]+bi);
      const float fv = sigm(acc[1][mi]+bfv);
      const float gv = tanha(acc[2][mi]+bg);
      const float ov = sigm(acc[3][mi]+bo);
      const float cold = (s>0) ? c_st[b*kH+j] : 0.f;
      const float c = fv*cold + iv*gv;
      c_st[b*kH+j] = c;
      h_next[(size_t)b*kH+j] = ov*tanha(c);
    }
  }
}

// ---------------- fwd/bwd reduce LSTM step: M=16384, K=512(+512) ----------------
// mode 0: X = const_emb[label_idx[n]] (f32), h/c treated as zero (no reads)
// mode 1: X = c0bf row (bf16, b*kS + 2r + xoff)
__global__ __launch_bounds__(256) void k_red_step(
    const u16* __restrict__ c0bf, const float* __restrict__ const_emb,
    const int* __restrict__ label_idx,
    const float* __restrict__ Wih, const float* __restrict__ Whh,
    const float* __restrict__ bias,
    const float* __restrict__ h_prev, float* __restrict__ h_next,
    float* __restrict__ c_st, int mode, int xoff)
{
  const int wid  = blockIdx.x*4 + (threadIdx.x>>6);
  const int lane = threadIdx.x & 63;
  const int jp = wid & 255;   // column pair: j0=jp, j1=jp+256
  const int mg = wid >> 8;    // 0..4095

  float x[4][8];
  float h[4][8];
  #pragma unroll
  for (int mi=0;mi<4;++mi){
    const int n = mg*4+mi;
    if (mode == 0){
      const float* xr = const_emb + (size_t)label_idx[n]*kH;
      #pragma unroll
      for (int i=0;i<8;++i) x[mi][i] = xr[i*64+lane];
    } else {
      const int b = n >> 7, r = n & 127;
      const u16* xr = c0bf + (size_t)(b*kS + 2*r + xoff)*kH;
      #pragma unroll
      for (int i=0;i<8;++i) x[mi][i] = bf(xr[i*64+lane]);
    }
  }
  if (mode != 0){
    #pragma unroll
    for (int mi=0;mi<4;++mi){
      const float* hp = h_prev + (size_t)(mg*4+mi)*kH;
      #pragma unroll
      for (int i=0;i<8;++i) h[mi][i] = hp[i*64+lane];
    }
  }

  float acc[2][4][4];
  #pragma unroll
  for (int jc=0;jc<2;++jc)
    #pragma unroll
    for (int g=0;g<4;++g)
      #pragma unroll
      for (int mi=0;mi<4;++mi) acc[jc][g][mi] = 0.f;

  #pragma unroll
  for (int jc=0;jc<2;++jc){
    const int j = jp + jc*256;
    #pragma unroll
    for (int g=0;g<4;++g){
      const float* wx = Wih + (size_t)(g*kH+j)*kH;
      #pragma unroll
      for (int i=0;i<8;++i){
        const float wv = wx[i*64+lane];
        #pragma unroll
        for (int mi=0;mi<4;++mi) acc[jc][g][mi] += x[mi][i]*wv;
      }
    }
  }
  if (mode != 0){
    #pragma unroll
    for (int jc=0;jc<2;++jc){
      const int j = jp + jc*256;
      #pragma unroll
      for (int g=0;g<4;++g){
        const float* wh = Whh + (size_t)(g*kH+j)*kH;
        #pragma unroll
        for (int i=0;i<8;++i){
          const float wv = wh[i*64+lane];
          #pragma unroll
          for (int mi=0;mi<4;++mi) acc[jc][g][mi] += h[mi][i]*wv;
        }
      }
    }
  }
  #pragma unroll
  for (int jc=0;jc<2;++jc)
    #pragma unroll
    for (int g=0;g<4;++g)
      #pragma unroll
      for (int mi=0;mi<4;++mi) acc[jc][g][mi] = wred(acc[jc][g][mi]);

  if (lane == 0){
    #pragma unroll
    for (int jc=0;jc<2;++jc){
      const int j = jp + jc*256;
      const float bi = bias[0*kH+j];
      const float bfv = bias[1*kH+j];
      const float bg = bias[2*kH+j];
      const float bo = bias[3*kH+j];
      #pragma unroll
      for (int mi=0;mi<4;++mi){
        const int n = mg*4+mi;
        const float iv = sigm(acc[jc][0][mi]+bi);
        const float fv = sigm(acc[jc][1][mi]+bfv);
        const float gv = tanha(acc[jc][2][mi]+bg);
        const float ov = sigm(acc[jc][3][mi]+bo);
        const float cold = (mode != 0) ? c_st[(size_t)n*kH+j] : 0.f;
        const float c = fv*cold + iv*gv;
        c_st[(size_t)n*kH+j] = c;
        h_next[(size_t)n*kH+j] = ov*tanha(c);
      }
    }
  }
}

// ---------------- w2c: c0 = word_h @ W^T + b, output bf16 (internal) ----------------
__global__ __launch_bounds__(256) void k_w2c(
    const float* __restrict__ word_h, const float* __restrict__ W,
    const float* __restrict__ bias, u16* __restrict__ c0bf)
{
  const int wid  = blockIdx.x*4 + (threadIdx.x>>6);
  const int lane = threadIdx.x & 63;
  const int jg = wid & 63;   // 8 columns each
  const int mg = wid >> 6;   // 0..8191

  float x[4][8];
  #pragma unroll
  for (int mi=0;mi<4;++mi){
    const float* xr = word_h + (size_t)(mg*4+mi)*kH;
    #pragma unroll
    for (int i=0;i<8;++i) x[mi][i] = xr[i*64+lane];
  }
  float acc[8][4];
  #pragma unroll
  for (int jc=0;jc<8;++jc)
    #pragma unroll
    for (int mi=0;mi<4;++mi) acc[jc][mi] = 0.f;

  #pragma unroll
  for (int i=0;i<8;++i){
    float wv[8];
    #pragma unroll
    for (int jc=0;jc<8;++jc) wv[jc] = W[(size_t)(jg*8+jc)*kH + i*64+lane];
    #pragma unroll
    for (int jc=0;jc<8;++jc)
      #pragma unroll
      for (int mi=0;mi<4;++mi) acc[jc][mi] += x[mi][i]*wv[jc];
  }
  #pragma unroll
  for (int jc=0;jc<8;++jc)
    #pragma unroll
    for (int mi=0;mi<4;++mi) acc[jc][mi] = wred(acc[jc][mi]);

  if (lane == 0){
    #pragma unroll
    for (int jc=0;jc<8;++jc){
      const int j = jg*8+jc;
      const float bv = bias[j];
      #pragma unroll
      for (int mi=0;mi<4;++mi)
        c0bf[(size_t)(mg*4+mi)*kH + j] = f2bf(acc[jc][mi]+bv);
    }
  }
}

// ---------------- red = tanh([fh|bh] @ W^T + b), f32 output ----------------
__global__ __launch_bounds__(256) void k_redmlp(
    const float* __restrict__ fh, const float* __restrict__ bh,
    const float* __restrict__ W, const float* __restrict__ bias,
    float* __restrict__ red)
{
  const int wid  = blockIdx.x*4 + (threadIdx.x>>6);
  const int lane = threadIdx.x & 63;
  const int jg = wid & 63;
  const int mg = wid >> 6;   // 0..4095

  float x1[4][8], x2[4][8];
  #pragma unroll
  for (int mi=0;mi<4;++mi){
    const float* a = fh + (size_t)(mg*4+mi)*kH;
    const float* b = bh + (size_t)(mg*4+mi)*kH;
    #pragma unroll
    for (int i=0;i<8;++i){ x1[mi][i] = a[i*64+lane]; x2[mi][i] = b[i*64+lane]; }
  }
  float acc[8][4];
  #pragma unroll
  for (int jc=0;jc<8;++jc)
    #pragma unroll
    for (int mi=0;mi<4;++mi) acc[jc][mi] = 0.f;

  #pragma unroll
  for (int i=0;i<8;++i){
    float wv[8];
    #pragma unroll
    for (int jc=0;jc<8;++jc) wv[jc] = W[(size_t)(jg*8+jc)*(2*kH) + i*64+lane];
    #pragma unroll
    for (int jc=0;jc<8;++jc)
      #pragma unroll
      for (int mi=0;mi<4;++mi) acc[jc][mi] += x1[mi][i]*wv[jc];
  }
  #pragma unroll
  for (int i=0;i<8;++i){
    float wv[8];
    #pragma unroll
    for (int jc=0;jc<8;++jc) wv[jc] = W[(size_t)(jg*8+jc)*(2*kH) + kH + i*64+lane];
    #pragma unroll
    for (int jc=0;jc<8;++jc)
      #pragma unroll
      for (int mi=0;mi<4;++mi) acc[jc][mi] += x2[mi][i]*wv[jc];
  }
  #pragma unroll
  for (int jc=0;jc<8;++jc)
    #pragma unroll
    for (int mi=0;mi<4;++mi) acc[jc][mi] = wred(acc[jc][mi]);

  if (lane == 0){
    #pragma unroll
    for (int jc=0;jc<8;++jc){
      const int j = jg*8+jc;
      const float bv = bias[j];
      #pragma unroll
      for (int mi=0;mi<4;++mi)
        red[(size_t)(mg*4+mi)*kH + j] = tanha(acc[jc][mi]+bv);
    }
  }
}

// ---------------- out = [word_h_last | tr_h | con_h] @ W^T + b, f32 out ----------------
__global__ __launch_bounds__(256) void k_out(
    const float* __restrict__ word_h, const float* __restrict__ tr_h,
    const float* __restrict__ con_h, const float* __restrict__ W,
    const float* __restrict__ bias, float* __restrict__ out)
{
  const int wid  = blockIdx.x*4 + (threadIdx.x>>6);
  const int lane = threadIdx.x & 63;
  const int b = wid / kNT;
  const int t = wid - b*kNT;
  const float* s0 = word_h + ((size_t)b*kS + (kS-1))*kH;
  const float* s1 = tr_h + (size_t)b*kH;
  const float* s2 = con_h + (size_t)b*kH;
  const float* wr = W + (size_t)t*(3*kH);
  float acc = 0.f;
  #pragma unroll
  for (int i=0;i<8;++i) acc += s0[i*64+lane]*wr[i*64+lane];
  #pragma unroll
  for (int i=0;i<8;++i) acc += s1[i*64+lane]*wr[kH + i*64+lane];
  #pragma unroll
  for (int i=0;i<8;++i) acc += s2[i*64+lane]*wr[2*kH + i*64+lane];
  acc = wred(acc);
  if (lane == 0) out[(size_t)b*kNT + t] = acc + bias[t];
}

extern "C" void kernel_launch(void* const* d_in, const int* in_sizes, int n_in,
                              void* d_out, int out_size, void* d_ws, size_t ws_size,
                              hipStream_t stream)
{
  (void)in_sizes; (void)n_in; (void)out_size; (void)ws_size;
  const int* word_idx = (const int*)d_in[0];
  const int* tag_idx  = (const int*)d_in[1];
  const int* tr_idx   = (const int*)d_in[2];
  const int* lab_idx  = (const int*)d_in[3];
  const float* emb       = (const float*)d_in[4];
  const float* tag_emb   = (const float*)d_in[5];
  const float* tr_emb    = (const float*)d_in[6];
  const float* const_emb = (const float*)d_in[7];
  const float* word_Wih = (const float*)d_in[8];
  const float* word_Whh = (const float*)d_in[9];
  const float* word_b   = (const float*)d_in[10];
  const float* tr_Wih = (const float*)d_in[11];
  const float* tr_Whh = (const float*)d_in[12];
  const float* tr_b   = (const float*)d_in[13];
  const float* con_Wih = (const float*)d_in[14];
  const float* con_Whh = (const float*)d_in[15];
  const float* con_b   = (const float*)d_in[16];
  const float* fwd_Wih = (const float*)d_in[17];
  const float* fwd_Whh = (const float*)d_in[18];
  const float* fwd_b   = (const float*)d_in[19];
  const float* bwd_Wih = (const float*)d_in[20];
  const float* bwd_Whh = (const float*)d_in[21];
  const float* bwd_b   = (const float*)d_in[22];
  const float* w2c_W = (const float*)d_in[23];
  const float* w2c_b = (const float*)d_in[24];
  const float* red_W = (const float*)d_in[25];
  const float* red_b = (const float*)d_in[26];
  const float* out_W = (const float*)d_in[27];
  const float* out_b = (const float*)d_in[28];

  char* p = (char*)d_ws;
  auto alloc = [&](size_t bytes)->void* {
    void* r = (void*)p; p += (bytes + 255) & ~(size_t)255; return r;
  };
  float* word_h = (float*)alloc((size_t)kB*kS*kH*sizeof(float));  // 64 MB
  u16*   c0bf   = (u16*)  alloc((size_t)kB*kS*kH*sizeof(u16));    // 32 MB
  float* hA = (float*)alloc((size_t)kB*kR*kH*sizeof(float));      // 32 MB
  float* hB = (float*)alloc((size_t)kB*kR*kH*sizeof(float));
  float* hC = (float*)alloc((size_t)kB*kR*kH*sizeof(float));
  float* cR = (float*)alloc((size_t)kB*kR*kH*sizeof(float));
  float* c_word = (float*)alloc((size_t)kB*kH*sizeof(float));
  float* trA    = (float*)alloc((size_t)kB*kH*sizeof(float));
  float* trB    = (float*)alloc((size_t)kB*kH*sizeof(float));
  float* c_tr   = (float*)alloc((size_t)kB*kH*sizeof(float));
  float* conA   = (float*)alloc((size_t)kB*kH*sizeof(float));
  float* conB   = (float*)alloc((size_t)kB*kH*sizeof(float));
  float* c_con  = (float*)alloc((size_t)kB*kH*sizeof(float));

  // 1) word LSTM, 256 sequential steps; h stored per-step into word_h
  for (int s=0;s<kS;++s)
    k_word_step<<<4096,256,0,stream>>>(word_idx, tag_idx, emb, tag_emb,
                                       word_Wih, word_Whh, word_b,
                                       word_h, c_word, s);
  // 2) c0 = w2c(word_h), bf16 internal
  k_w2c<<<131072,256,0,stream>>>(word_h, w2c_W, w2c_b, c0bf);
  // 3) fwd reduce LSTM: [lab, ch0, ch1] -> fh in hA
  k_red_step<<<262144,256,0,stream>>>(c0bf, const_emb, lab_idx, fwd_Wih, fwd_Whh, fwd_b, nullptr, hA, cR, 0, 0);
  k_red_step<<<262144,256,0,stream>>>(c0bf, const_emb, lab_idx, fwd_Wih, fwd_Whh, fwd_b, hA, hB, cR, 1, 0);
  k_red_step<<<262144,256,0,stream>>>(c0bf, const_emb, lab_idx, fwd_Wih, fwd_Whh, fwd_b, hB, hA, cR, 1, 1);
  // 4) bwd reduce LSTM: [lab, ch1, ch0] -> bh in hB
  k_red_step<<<262144,256,0,stream>>>(c0bf, const_emb, lab_idx, bwd_Wih, bwd_Whh, bwd_b, nullptr, hB, cR, 0, 0);
  k_red_step<<<262144,256,0,stream>>>(c0bf, const_emb, lab_idx, bwd_Wih, bwd_Whh, bwd_b, hB, hC, cR, 1, 1);
  k_red_step<<<262144,256,0,stream>>>(c0bf, const_emb, lab_idx, bwd_Wih, bwd_Whh, bwd_b, hC, hB, cR, 1, 0);
  // 5) red = tanh([fh|bh] @ red_W^T + b) -> hC (layout [B,R,H])
  k_redmlp<<<65536,256,0,stream>>>(hA, hB, red_W, red_b, hC);
  // 6) constituent LSTM over red, 128 steps
  float* hp = conA; float* hn = conB;
  for (int s=0;s<kR;++s){
    k_con_step<<<4096,256,0,stream>>>(hC, con_Wih, con_Whh, con_b, hp, hn, c_con, s);
    float* t = hp; hp = hn; hn = t;
  }
  float* con_final = hp;
  // 7) transition LSTM, 512 steps
  hp = trA; hn = trB;
  for (int s=0;s<kT;++s){
    k_tr_step<<<4096,256,0,stream>>>(tr_idx, tr_emb, tr_Wih, tr_Whh, tr_b, hp, hn, c_tr, s);
    float* t = hp; hp = hn; hn = t;
  }
  float* tr_final = hp;
  // 8) output projection
  k_out<<<3200,256,0,stream>>>(word_h, tr_final, con_final, out_W, out_b, (float*)d_out);
}

// Round 4
// 20862.183 us; speedup vs baseline: 2.6004x; 2.6004x over previous
//
#include <hip/hip_runtime.h>

typedef unsigned short u16;
typedef unsigned int u32;
typedef __attribute__((ext_vector_type(8))) short short8;
typedef __attribute__((ext_vector_type(4))) float f32x4;

namespace {
constexpr int kS  = 256;
constexpr int kT  = 512;
constexpr int kR  = 128;
constexpr int kNT = 100;
constexpr int LDST = 40;   // LDS row stride (bf16) for 32-wide K chunks
}

__device__ __forceinline__ float bf(u16 v){ return __uint_as_float(((u32)v)<<16); }
__device__ __forceinline__ u16 f2bf(float f){
  u32 u = __float_as_uint(f);
  return (u16)((u + 0x7fffu + ((u>>16)&1u)) >> 16);
}
__device__ __forceinline__ float sigm(float x){ return 1.f/(1.f+__expf(-x)); }
__device__ __forceinline__ float tanha(float x){ return 2.f/(1.f+__expf(-2.f*x)) - 1.f; }
__device__ __forceinline__ float wred(float v){
  #pragma unroll
  for (int off=32; off>0; off>>=1) v += __shfl_xor(v, off, 64);
  return v;
}

// ---------------- shared MFMA K-loop core (linear A): 128x128 C-tile, BK=32 ----------------
__device__ __forceinline__ void gemm_core(
    const u16* __restrict__ A, const u16* __restrict__ B, int K,
    int m0, int n0, u16* As, u16* Bs, f32x4 acc[4][4], int tid)
{
  const int lane = tid & 63;
  const int w = tid >> 6;
  const int wm = (w & 1) * 64, wn = (w >> 1) * 64;
  const int fr = lane & 15;
  const int fq = (lane >> 4) * 8;
  for (int k0 = 0; k0 < K; k0 += 32) {
    __syncthreads();
    #pragma unroll
    for (int it = 0; it < 2; ++it) {
      const int l = tid + it * 256;
      const int r = l >> 2, kq = (l & 3) * 8;
      *(uint4*)&As[r * LDST + kq] = *(const uint4*)&A[(size_t)(m0 + r) * K + k0 + kq];
      *(uint4*)&Bs[r * LDST + kq] = *(const uint4*)&B[(size_t)(n0 + r) * K + k0 + kq];
    }
    __syncthreads();
    short8 af[4], bfr[4];
    #pragma unroll
    for (int t = 0; t < 4; ++t) {
      af[t]  = *(const short8*)&As[(wm + t * 16 + fr) * LDST + fq];
      bfr[t] = *(const short8*)&Bs[(wn + t * 16 + fr) * LDST + fq];
    }
    #pragma unroll
    for (int mt = 0; mt < 4; ++mt)
      #pragma unroll
      for (int nt = 0; nt < 4; ++nt)
        acc[mt][nt] = __builtin_amdgcn_mfma_f32_16x16x32_bf16(af[mt], bfr[nt], acc[mt][nt], 0, 0, 0);
  }
}

// ---------------- plain GEMM: C = A @ B^T (+bias) (opt tanh), C bf16 ----------------
__global__ __launch_bounds__(256) void k_gemm(
    const u16* __restrict__ A, const u16* __restrict__ B, u16* __restrict__ C,
    const float* __restrict__ bias, int K, int N, int tanh_flag)
{
  __shared__ u16 As[128 * LDST];
  __shared__ u16 Bs[128 * LDST];
  const int tid = threadIdx.x;
  const int m0 = blockIdx.x * 128, n0 = blockIdx.y * 128;
  f32x4 acc[4][4];
  const f32x4 z4 = {0.f, 0.f, 0.f, 0.f};
  #pragma unroll
  for (int mt = 0; mt < 4; ++mt)
    #pragma unroll
    for (int nt = 0; nt < 4; ++nt) acc[mt][nt] = z4;

  gemm_core(A, B, K, m0, n0, As, Bs, acc, tid);

  const int lane = tid & 63;
  const int w = tid >> 6;
  const int wm = (w & 1) * 64, wn = (w >> 1) * 64;
  const int cr = (lane >> 4) * 4, cc = lane & 15;
  #pragma unroll
  for (int mt = 0; mt < 4; ++mt)
    #pragma unroll
    for (int nt = 0; nt < 4; ++nt)
      #pragma unroll
      for (int ri = 0; ri < 4; ++ri) {
        const int row = m0 + wm + mt * 16 + cr + ri;
        const int col = n0 + wn + nt * 16 + cc;
        float v = acc[mt][nt][ri];
        if (bias) v += bias[col];
        if (tanh_flag) v = tanha(v);
        C[(size_t)row * N + col] = f2bf(v);
      }
}

// ---------------- fused step with precomputed XG (word / transition) ----------------
// Z = h_prev @ Whh^T ; gates(Z + XG[row]) ; xg_mode 0: xr=m*p0 ; xg_mode 2: xr=idx[m*istride]
__global__ __launch_bounds__(256) void k_gemm_lstm(
    const u16* __restrict__ A, const u16* __restrict__ B,
    const u16* __restrict__ xg, int xg_mode, int p0,
    const int* __restrict__ idx, int istride,
    float* __restrict__ c_st, u16* __restrict__ h_out, int h_stride, int h_coloff)
{
  __shared__ u16 As[128 * LDST];
  __shared__ u16 Bs[128 * LDST];
  __shared__ float zb[64 * 128];
  const int tid = threadIdx.x;
  const int m0 = blockIdx.x * 128, n0 = blockIdx.y * 128;
  f32x4 acc[4][4];
  const f32x4 z4 = {0.f, 0.f, 0.f, 0.f};
  #pragma unroll
  for (int mt = 0; mt < 4; ++mt)
    #pragma unroll
    for (int nt = 0; nt < 4; ++nt) acc[mt][nt] = z4;

  gemm_core(A, B, 512, m0, n0, As, Bs, acc, tid);

  const int lane = tid & 63;
  const int w = tid >> 6;
  const int wm = (w & 1) * 64, wn = (w >> 1) * 64;
  const int cr = (lane >> 4) * 4, cc = lane & 15;

  #pragma unroll
  for (int half = 0; half < 2; ++half) {
    __syncthreads();
    if (wm == half * 64) {
      #pragma unroll
      for (int mt = 0; mt < 4; ++mt)
        #pragma unroll
        for (int nt = 0; nt < 4; ++nt)
          #pragma unroll
          for (int ri = 0; ri < 4; ++ri)
            zb[(mt * 16 + cr + ri) * 128 + wn + nt * 16 + cc] = acc[mt][nt][ri];
    }
    __syncthreads();
    for (int c = tid; c < 2048; c += 256) {
      const int rl = c >> 5;
      const int q  = c & 31;
      const int m  = m0 + half * 64 + rl;
      const int jh = (n0 >> 2) + q;
      long xr;
      if (xg_mode == 0) xr = (long)m * p0;
      else              xr = (long)idx[(size_t)m * istride];
      const ushort4 xq = *(const ushort4*)&xg[xr * 2048 + n0 + q * 4];
      const float4 zv = *(const float4*)&zb[rl * 128 + q * 4];
      const float i_ = sigm(zv.x + bf(xq.x));
      const float f_ = sigm(zv.y + bf(xq.y));
      const float g_ = tanha(zv.z + bf(xq.z));
      const float o_ = sigm(zv.w + bf(xq.w));
      const size_t ci = (size_t)m * 512 + jh;
      const float cn = f_ * c_st[ci] + i_ * g_;
      c_st[ci] = cn;
      h_out[(size_t)m * h_stride + h_coloff + jh] = f2bf(o_ * tanha(cn));
    }
  }
}

// ---------------- fused concat-K step: gates = [h | x] @ [Whh|Wih]^T + b ----------------
// K=1024 (cols 0..511 = h from H rows linear m; 512..1023 = x from X rows via cmode)
// cmode 1: xr=(2*(m&127)+p0)*128+(m>>7) [reduce children, X=c0]
// cmode 2: xr=idx[m]                     [labels, X=A80]
// cmode 3: xr=m*128+p0                   [con, X=red]
// first=1: skip h half entirely, c_old = 0
__global__ __launch_bounds__(256) void k_lstm_cat(
    const u16* __restrict__ H, const u16* __restrict__ X,
    const u16* __restrict__ B, const float* __restrict__ bias,
    const int* __restrict__ idx, int cmode, int p0, int first,
    float* __restrict__ c_st, u16* __restrict__ h_out, int h_stride, int h_coloff)
{
  __shared__ u16 As[128 * LDST];
  __shared__ u16 Bs[128 * LDST];
  __shared__ float zb[64 * 128];
  const int tid = threadIdx.x;
  const int m0 = blockIdx.x * 128, n0 = blockIdx.y * 128;
  const int lane = tid & 63;
  const int w = tid >> 6;
  const int wm = (w & 1) * 64, wn = (w >> 1) * 64;
  const int fr = lane & 15, fq = (lane >> 4) * 8;
  f32x4 acc[4][4];
  const f32x4 z4 = {0.f, 0.f, 0.f, 0.f};
  #pragma unroll
  for (int mt = 0; mt < 4; ++mt)
    #pragma unroll
    for (int nt = 0; nt < 4; ++nt) acc[mt][nt] = z4;

  for (int k0 = first ? 512 : 0; k0 < 1024; k0 += 32) {
    __syncthreads();
    #pragma unroll
    for (int it = 0; it < 2; ++it) {
      const int l = tid + it * 256;
      const int r = l >> 2, kq = (l & 3) * 8;
      const int m = m0 + r;
      const u16* src;
      if (k0 < 512) {
        src = H + (size_t)m * 512 + k0 + kq;
      } else {
        long xr;
        if (cmode == 1)      xr = (long)(2 * (m & 127) + p0) * 128 + (m >> 7);
        else if (cmode == 2) xr = (long)idx[m];
        else                 xr = (long)m * 128 + p0;
        src = X + (size_t)xr * 512 + (k0 - 512) + kq;
      }
      *(uint4*)&As[r * LDST + kq] = *(const uint4*)src;
      *(uint4*)&Bs[r * LDST + kq] = *(const uint4*)&B[(size_t)(n0 + r) * 1024 + k0 + kq];
    }
    __syncthreads();
    short8 af[4], bfr[4];
    #pragma unroll
    for (int t = 0; t < 4; ++t) {
      af[t]  = *(const short8*)&As[(wm + t * 16 + fr) * LDST + fq];
      bfr[t] = *(const short8*)&Bs[(wn + t * 16 + fr) * LDST + fq];
    }
    #pragma unroll
    for (int mt = 0; mt < 4; ++mt)
      #pragma unroll
      for (int nt = 0; nt < 4; ++nt)
        acc[mt][nt] = __builtin_amdgcn_mfma_f32_16x16x32_bf16(af[mt], bfr[nt], acc[mt][nt], 0, 0, 0);
  }

  const int cr = (lane >> 4) * 4, cc = lane & 15;
  #pragma unroll
  for (int half = 0; half < 2; ++half) {
    __syncthreads();
    if (wm == half * 64) {
      #pragma unroll
      for (int mt = 0; mt < 4; ++mt)
        #pragma unroll
        for (int nt = 0; nt < 4; ++nt)
          #pragma unroll
          for (int ri = 0; ri < 4; ++ri)
            zb[(mt * 16 + cr + ri) * 128 + wn + nt * 16 + cc] = acc[mt][nt][ri];
    }
    __syncthreads();
    for (int c = tid; c < 2048; c += 256) {
      const int rl = c >> 5;
      const int q  = c & 31;
      const int m  = m0 + half * 64 + rl;
      const int jh = (n0 >> 2) + q;
      const float4 bv = *(const float4*)&bias[n0 + q * 4];
      const float4 zv = *(const float4*)&zb[rl * 128 + q * 4];
      const float i_ = sigm(zv.x + bv.x);
      const float f_ = sigm(zv.y + bv.y);
      const float g_ = tanha(zv.z + bv.z);
      const float o_ = sigm(zv.w + bv.w);
      const size_t ci = (size_t)m * 512 + jh;
      const float cold = first ? 0.f : c_st[ci];
      const float cn = f_ * cold + i_ * g_;
      c_st[ci] = cn;
      h_out[(size_t)m * h_stride + h_coloff + jh] = f2bf(o_ * tanha(cn));
    }
  }
}

// ---------------- first LSTM step from XG table (no h) ----------------
__global__ __launch_bounds__(256) void k_gate0(
    const u16* __restrict__ xg, int xg_mode, int p0,
    const int* __restrict__ idx, int istride,
    float* __restrict__ c_st, u16* __restrict__ h_out, int h_stride, int h_coloff, int M)
{
  const int id = blockIdx.x * 256 + threadIdx.x;
  if (id >= M * 512) return;
  const int m = id >> 9, jh = id & 511;
  long xr;
  if (xg_mode == 0) xr = (long)m * p0;
  else              xr = (long)idx[(size_t)m * istride];
  const ushort4 xq = *(const ushort4*)&xg[xr * 2048 + jh * 4];
  const float i_ = sigm(bf(xq.x));
  const float g_ = tanha(bf(xq.z));
  const float o_ = sigm(bf(xq.w));
  const float cn = i_ * g_;
  c_st[(size_t)m * 512 + jh] = cn;
  h_out[(size_t)m * h_stride + h_coloff + jh] = f2bf(o_ * tanha(cn));
}

// ---------------- preps ----------------
// gate-interleave rows (row' = 4*jh + g), f32->bf16, write into [coff, coff+Kfill) of Ktot-wide out
__global__ void k_perm_w(const float* __restrict__ in, u16* __restrict__ out,
                         int Ksrc, int Kfill, int Ktot, int coff)
{
  const int rp = blockIdx.x;             // 0..2047
  const int g = rp & 3, jh = rp >> 2;
  const float* src = in + (size_t)(g * 512 + jh) * Ksrc;
  for (int k = threadIdx.x; k < Kfill; k += 256)
    out[(size_t)rp * Ktot + coff + k] = f2bf(k < Ksrc ? src[k] : 0.f);
}
__global__ void k_perm_b(const float* __restrict__ in, float* __restrict__ out)
{
  const int rp = blockIdx.x * 256 + threadIdx.x;
  out[rp] = in[(rp & 3) * 512 + (rp >> 2)];
}
__global__ void k_cvt(const float* __restrict__ in, u16* __restrict__ out, int n)
{
  const int i = blockIdx.x * 256 + threadIdx.x;
  if (i < n) out[i] = f2bf(in[i]);
}
__global__ void k_pad2d(const float* __restrict__ in, u16* __restrict__ out,
                        int Rin, int Kin, int Kout)
{
  const int r = blockIdx.x;
  for (int k = threadIdx.x; k < Kout; k += 256)
    out[(size_t)r * Kout + k] = f2bf((r < Rin && k < Kin) ? in[(size_t)r * Kin + k] : 0.f);
}
__global__ void k_gather_word(const int* __restrict__ widx, const int* __restrict__ tidx,
                              const float* __restrict__ emb, const float* __restrict__ temb,
                              u16* __restrict__ Aw)
{
  const int row = blockIdx.x;            // 0..32767 = s*128+b
  const int s = row >> 7, b = row & 127;
  const int wi = widx[b * kS + s];
  const int ti = tidx[b * kS + s];
  for (int t = threadIdx.x; t < 320; t += 256)
    Aw[(size_t)row * 320 + t] = f2bf(t < 300 ? emb[(size_t)wi * 300 + t] : temb[ti * 20 + t - 300]);
}

// ---------------- out = [word_h_last | tr_h | con_h] @ W^T + b ----------------
__global__ __launch_bounds__(256) void k_out(
    const u16* __restrict__ wh, const u16* __restrict__ trh, const u16* __restrict__ conh,
    const float* __restrict__ W, const float* __restrict__ bias, float* __restrict__ out)
{
  const int wid = blockIdx.x * 4 + (threadIdx.x >> 6);
  const int lane = threadIdx.x & 63;
  const int b = wid / kNT;
  const int t = wid - b * kNT;
  const u16* s0 = wh + (size_t)b * 512;
  const u16* s1 = trh + (size_t)b * 512;
  const u16* s2 = conh + (size_t)b * 512;
  const float* wr = W + (size_t)t * 1536;
  float acc = 0.f;
  #pragma unroll
  for (int i = 0; i < 8; ++i) acc += bf(s0[i * 64 + lane]) * wr[i * 64 + lane];
  #pragma unroll
  for (int i = 0; i < 8; ++i) acc += bf(s1[i * 64 + lane]) * wr[512 + i * 64 + lane];
  #pragma unroll
  for (int i = 0; i < 8; ++i) acc += bf(s2[i * 64 + lane]) * wr[1024 + i * 64 + lane];
  acc = wred(acc);
  if (lane == 0) out[(size_t)b * kNT + t] = acc + bias[t];
}

extern "C" void kernel_launch(void* const* d_in, const int* in_sizes, int n_in,
                              void* d_out, int out_size, void* d_ws, size_t ws_size,
                              hipStream_t stream)
{
  (void)in_sizes; (void)n_in; (void)out_size; (void)ws_size;
  const int* word_idx = (const int*)d_in[0];
  const int* tag_idx  = (const int*)d_in[1];
  const int* tr_idx   = (const int*)d_in[2];
  const int* lab_idx  = (const int*)d_in[3];
  const float* emb       = (const float*)d_in[4];
  const float* tag_emb   = (const float*)d_in[5];
  const float* tr_emb    = (const float*)d_in[6];
  const float* const_emb = (const float*)d_in[7];
  const float* word_Wih = (const float*)d_in[8];
  const float* word_Whh = (const float*)d_in[9];
  const float* word_b   = (const float*)d_in[10];
  const float* tr_Wih = (const float*)d_in[11];
  const float* tr_Whh = (const float*)d_in[12];
  const float* tr_b   = (const float*)d_in[13];
  const float* con_Wih = (const float*)d_in[14];
  const float* con_Whh = (const float*)d_in[15];
  const float* con_b   = (const float*)d_in[16];
  const float* fwd_Wih = (const float*)d_in[17];
  const float* fwd_Whh = (const float*)d_in[18];
  const float* fwd_b   = (const float*)d_in[19];
  const float* bwd_Wih = (const float*)d_in[20];
  const float* bwd_Whh = (const float*)d_in[21];
  const float* bwd_b   = (const float*)d_in[22];
  const float* w2c_W = (const float*)d_in[23];
  const float* w2c_b = (const float*)d_in[24];
  const float* red_W = (const float*)d_in[25];
  const float* red_b = (const float*)d_in[26];
  const float* out_W = (const float*)d_in[27];
  const float* out_b = (const float*)d_in[28];

  char* p = (char*)d_ws;
  auto alloc = [&](size_t bytes)->void* {
    void* r = (void*)p; p += (bytes + 255) & ~(size_t)255; return r;
  };
  // -------- arena (~189 MB total; aliased lifetimes) --------
  u16* word_h = (u16*)alloc((size_t)32768*512*2);        // 33.55 MB, whole run
  char* R2    = (char*)alloc((size_t)32768*512*2);       // c0 (w2c..bwd step3) / red (after)
  char* R3    = (char*)alloc((size_t)16384*512*4);       // A_word (word phase) / c_big (reduce)
  char* R4    = (char*)alloc((size_t)16384*1024*2);      // XGbuf (word) / fb (reduce on)
  u16* h1     = (u16*)alloc((size_t)16384*512*2);        // 16.78 MB
  u16* h2     = (u16*)alloc((size_t)16384*512*2);
  u16* c0     = (u16*)R2;
  u16* red    = (u16*)R2;           // alias: c0 dead before red written
  u16* A_word = (u16*)R3;           // 21.0 MB < 33.55
  float* c_big= (float*)R3;         // alias: A_word dead before c_big written
  u16* XGbuf  = (u16*)R4;           // 33.55 MB (64-step word chunks)
  u16* fb     = (u16*)R4;           // alias: XGbuf dead before fb written
  // weights / small
  u16* wWih = (u16*)alloc((size_t)2048*320*2);
  u16* wWhh = (u16*)alloc((size_t)2048*512*2);
  u16* tWih = (u16*)alloc((size_t)2048*32*2);
  u16* tWhh = (u16*)alloc((size_t)2048*512*2);
  u16* cWcat = (u16*)alloc((size_t)2048*1024*2);
  u16* fWcat = (u16*)alloc((size_t)2048*1024*2);
  u16* bWcat = (u16*)alloc((size_t)2048*1024*2);
  u16* w2cWb = (u16*)alloc((size_t)512*512*2);
  u16* redWb = (u16*)alloc((size_t)512*1024*2);
  u16* A80   = (u16*)alloc((size_t)128*512*2);
  u16* Atr   = (u16*)alloc((size_t)128*32*2);
  u16* tbltr = (u16*)alloc((size_t)128*2048*2);
  float* b_word = (float*)alloc(2048*4);
  float* b_tr   = (float*)alloc(2048*4);
  float* b_con  = (float*)alloc(2048*4);
  float* b_fwd  = (float*)alloc(2048*4);
  float* b_bwd  = (float*)alloc(2048*4);
  float* c_sm  = (float*)alloc((size_t)128*512*4);
  u16* trh1 = (u16*)alloc((size_t)128*512*2);
  u16* trh2 = (u16*)alloc((size_t)128*512*2);
  u16* ch1  = (u16*)alloc((size_t)128*512*2);
  u16* ch2  = (u16*)alloc((size_t)128*512*2);

  // ---- preps ----
  k_perm_w<<<2048,256,0,stream>>>(word_Wih, wWih, 320, 320, 320, 0);
  k_perm_w<<<2048,256,0,stream>>>(word_Whh, wWhh, 512, 512, 512, 0);
  k_perm_w<<<2048,256,0,stream>>>(tr_Wih,   tWih, 20,  32,  32,  0);
  k_perm_w<<<2048,256,0,stream>>>(tr_Whh,   tWhh, 512, 512, 512, 0);
  k_perm_w<<<2048,256,0,stream>>>(con_Whh,  cWcat, 512, 512, 1024, 0);
  k_perm_w<<<2048,256,0,stream>>>(con_Wih,  cWcat, 512, 512, 1024, 512);
  k_perm_w<<<2048,256,0,stream>>>(fwd_Whh,  fWcat, 512, 512, 1024, 0);
  k_perm_w<<<2048,256,0,stream>>>(fwd_Wih,  fWcat, 512, 512, 1024, 512);
  k_perm_w<<<2048,256,0,stream>>>(bwd_Whh,  bWcat, 512, 512, 1024, 0);
  k_perm_w<<<2048,256,0,stream>>>(bwd_Wih,  bWcat, 512, 512, 1024, 512);
  k_perm_b<<<8,256,0,stream>>>(word_b, b_word);
  k_perm_b<<<8,256,0,stream>>>(tr_b,   b_tr);
  k_perm_b<<<8,256,0,stream>>>(con_b,  b_con);
  k_perm_b<<<8,256,0,stream>>>(fwd_b,  b_fwd);
  k_perm_b<<<8,256,0,stream>>>(bwd_b,  b_bwd);
  k_cvt<<<1024,256,0,stream>>>(w2c_W, w2cWb, 512*512);
  k_cvt<<<2048,256,0,stream>>>(red_W, redWb, 512*1024);
  k_pad2d<<<128,256,0,stream>>>(const_emb, A80, 80, 512, 512);
  k_pad2d<<<128,256,0,stream>>>(tr_emb,    Atr, 100, 20, 32);
  k_gather_word<<<32768,256,0,stream>>>(word_idx, tag_idx, emb, tag_emb, A_word);

  // ---- word LSTM (XG in 4 chunks of 64 steps) ----
  for (int c = 0; c < 4; ++c) {
    k_gemm<<<dim3(64,16),256,0,stream>>>(A_word + (size_t)c*8192*320, wWih, XGbuf,
                                         b_word, 320, 2048, 0);
    const int s_begin = (c == 0) ? 1 : c*64;
    if (c == 0)
      k_gate0<<<256,256,0,stream>>>(XGbuf, 0, 1, nullptr, 0, c_sm, word_h, 512, 0, 128);
    for (int s = s_begin; s < c*64 + 64; ++s)
      k_gemm_lstm<<<dim3(1,16),256,0,stream>>>(
          word_h + (size_t)(s-1)*128*512, wWhh,
          XGbuf + (size_t)(s & 63)*128*2048, 0, 1, nullptr, 0,
          c_sm, word_h + (size_t)s*128*512, 512, 0);
  }

  // ---- w2c: c0 = word_h @ w2c_W^T + b (bf16) ----
  k_gemm<<<dim3(256,4),256,0,stream>>>(word_h, w2cWb, c0, w2c_b, 512, 512, 0);

  // ---- fwd reduce (concat-K fused steps) ----
  k_lstm_cat<<<dim3(128,16),256,0,stream>>>(h1, A80, fWcat, b_fwd, lab_idx, 2, 0, 1, c_big, h1, 512, 0);
  k_lstm_cat<<<dim3(128,16),256,0,stream>>>(h1, c0,  fWcat, b_fwd, nullptr, 1, 0, 0, c_big, h2, 512, 0);
  k_lstm_cat<<<dim3(128,16),256,0,stream>>>(h2, c0,  fWcat, b_fwd, nullptr, 1, 1, 0, c_big, fb, 1024, 0);
  // ---- bwd reduce ----
  k_lstm_cat<<<dim3(128,16),256,0,stream>>>(h1, A80, bWcat, b_bwd, lab_idx, 2, 0, 1, c_big, h1, 512, 0);
  k_lstm_cat<<<dim3(128,16),256,0,stream>>>(h1, c0,  bWcat, b_bwd, nullptr, 1, 1, 0, c_big, h2, 512, 0);
  k_lstm_cat<<<dim3(128,16),256,0,stream>>>(h2, c0,  bWcat, b_bwd, nullptr, 1, 0, 0, c_big, fb, 1024, 512);

  // ---- red = tanh([fh|bh] @ red_W^T + b) (c0 dead; red aliases it) ----
  k_gemm<<<dim3(128,4),256,0,stream>>>(fb, redWb, red, red_b, 1024, 512, 1);

  // ---- constituent LSTM (concat-K fused steps, M=128) ----
  k_lstm_cat<<<dim3(1,16),256,0,stream>>>(ch1, red, cWcat, b_con, nullptr, 3, 0, 1, c_sm, ch1, 512, 0);
  u16* chp = ch1; u16* chn = ch2;
  for (int s = 1; s < kR; ++s) {
    k_lstm_cat<<<dim3(1,16),256,0,stream>>>(chp, red, cWcat, b_con, nullptr, 3, s, 0, c_sm, chn, 512, 0);
    u16* t = chp; chp = chn; chn = t;
  }
  u16* con_final = chp;

  // ---- transition LSTM (XG table + fused steps) ----
  k_gemm<<<dim3(1,16),256,0,stream>>>(Atr, tWih, tbltr, b_tr, 32, 2048, 0);
  k_gate0<<<256,256,0,stream>>>(tbltr, 2, 0, tr_idx, 512, c_sm, trh1, 512, 0, 128);
  u16* thp = trh1; u16* thn = trh2;
  for (int s = 1; s < kT; ++s) {
    k_gemm_lstm<<<dim3(1,16),256,0,stream>>>(thp, tWhh, tbltr, 2, 0, tr_idx + s, 512,
                                             c_sm, thn, 512, 0);
    u16* t = thp; thp = thn; thn = t;
  }
  u16* tr_final = thp;

  // ---- output ----
  k_out<<<3200,256,0,stream>>>(word_h + (size_t)255*128*512, tr_final, con_final,
                               out_W, out_b, (float*)d_out);
}

// Round 5
// 20817.426 us; speedup vs baseline: 2.6060x; 1.0021x over previous
//
#include <hip/hip_runtime.h>

typedef unsigned short u16;
typedef unsigned int u32;
typedef __attribute__((ext_vector_type(8))) short short8;
typedef __attribute__((ext_vector_type(4))) float f32x4;

namespace {
constexpr int kS  = 256;
constexpr int kT  = 512;
constexpr int kR  = 128;
constexpr int kNT = 100;
constexpr int LDST = 40;   // LDS row stride (bf16) for 32-wide K chunks
}

__device__ __forceinline__ float bf(u16 v){ return __uint_as_float(((u32)v)<<16); }
__device__ __forceinline__ u16 f2bf(float f){
  u32 u = __float_as_uint(f);
  return (u16)((u + 0x7fffu + ((u>>16)&1u)) >> 16);
}
__device__ __forceinline__ float sigm(float x){ return 1.f/(1.f+__expf(-x)); }
__device__ __forceinline__ float tanha(float x){ return 2.f/(1.f+__expf(-2.f*x)) - 1.f; }
__device__ __forceinline__ float wred(float v){
  #pragma unroll
  for (int off=32; off>0; off>>=1) v += __shfl_xor(v, off, 64);
  return v;
}

// device-scope grid barrier (16 co-resident blocks)
__device__ __forceinline__ void gbar(u32* cnt, u32 target){
  __threadfence();
  __syncthreads();
  if (threadIdx.x == 0){
    __hip_atomic_fetch_add(cnt, 1u, __ATOMIC_RELEASE, __HIP_MEMORY_SCOPE_AGENT);
    while (__hip_atomic_load(cnt, __ATOMIC_ACQUIRE, __HIP_MEMORY_SCOPE_AGENT) < target)
      __builtin_amdgcn_s_sleep(1);
  }
  __syncthreads();
  __threadfence();
}

__global__ void k_zero(u32* p, int n){
  const int i = blockIdx.x*256 + threadIdx.x;
  if (i < n) p[i] = 0;
}

// ---------------- shared MFMA K-loop core (linear A): 128x128 C-tile, BK=32 ----------------
__device__ __forceinline__ void gemm_core(
    const u16* __restrict__ A, const u16* __restrict__ B, int K,
    int m0, int n0, u16* As, u16* Bs, f32x4 acc[4][4], int tid)
{
  const int lane = tid & 63;
  const int w = tid >> 6;
  const int wm = (w & 1) * 64, wn = (w >> 1) * 64;
  const int fr = lane & 15;
  const int fq = (lane >> 4) * 8;
  for (int k0 = 0; k0 < K; k0 += 32) {
    __syncthreads();
    #pragma unroll
    for (int it = 0; it < 2; ++it) {
      const int l = tid + it * 256;
      const int r = l >> 2, kq = (l & 3) * 8;
      *(uint4*)&As[r * LDST + kq] = *(const uint4*)&A[(size_t)(m0 + r) * K + k0 + kq];
      *(uint4*)&Bs[r * LDST + kq] = *(const uint4*)&B[(size_t)(n0 + r) * K + k0 + kq];
    }
    __syncthreads();
    short8 af[4], bfr[4];
    #pragma unroll
    for (int t = 0; t < 4; ++t) {
      af[t]  = *(const short8*)&As[(wm + t * 16 + fr) * LDST + fq];
      bfr[t] = *(const short8*)&Bs[(wn + t * 16 + fr) * LDST + fq];
    }
    #pragma unroll
    for (int mt = 0; mt < 4; ++mt)
      #pragma unroll
      for (int nt = 0; nt < 4; ++nt)
        acc[mt][nt] = __builtin_amdgcn_mfma_f32_16x16x32_bf16(af[mt], bfr[nt], acc[mt][nt], 0, 0, 0);
  }
}

// ---------------- plain GEMM: C = A @ B^T (+bias) (opt tanh), C bf16 ----------------
__global__ __launch_bounds__(256) void k_gemm(
    const u16* __restrict__ A, const u16* __restrict__ B, u16* __restrict__ C,
    const float* __restrict__ bias, int K, int N, int tanh_flag)
{
  __shared__ u16 As[128 * LDST];
  __shared__ u16 Bs[128 * LDST];
  const int tid = threadIdx.x;
  const int m0 = blockIdx.x * 128, n0 = blockIdx.y * 128;
  f32x4 acc[4][4];
  const f32x4 z4 = {0.f, 0.f, 0.f, 0.f};
  #pragma unroll
  for (int mt = 0; mt < 4; ++mt)
    #pragma unroll
    for (int nt = 0; nt < 4; ++nt) acc[mt][nt] = z4;

  gemm_core(A, B, K, m0, n0, As, Bs, acc, tid);

  const int lane = tid & 63;
  const int w = tid >> 6;
  const int wm = (w & 1) * 64, wn = (w >> 1) * 64;
  const int cr = (lane >> 4) * 4, cc = lane & 15;
  #pragma unroll
  for (int mt = 0; mt < 4; ++mt)
    #pragma unroll
    for (int nt = 0; nt < 4; ++nt)
      #pragma unroll
      for (int ri = 0; ri < 4; ++ri) {
        const int row = m0 + wm + mt * 16 + cr + ri;
        const int col = n0 + wn + nt * 16 + cc;
        float v = acc[mt][nt][ri];
        if (bias) v += bias[col];
        if (tanh_flag) v = tanha(v);
        C[(size_t)row * N + col] = f2bf(v);
      }
}

// ---------------- persistent sequential LSTM (word / transition), 16 blocks ----------------
// seq_mode 1 (word): A = hseq+(s-1)*64K, out = hseq+s*64K, xg row = m, chunked xg (s&63)
// seq_mode 0 (tr):   A/out ping-pong hb0/hb1 by parity, xg row = idx[m*512+s], fixed table
__global__ __launch_bounds__(256) void k_seq_lstm(
    u16* hseq, u16* hb0, u16* hb1,
    const u16* __restrict__ B, const u16* __restrict__ xg,
    const int* __restrict__ idx,
    float* __restrict__ c_st, int s_begin, int s_end, int seq_mode, u32* cnt)
{
  __shared__ u16 As[128 * LDST];
  __shared__ u16 Bs[128 * LDST];
  __shared__ float zb[64 * 128];
  const int tid = threadIdx.x;
  const int n0 = blockIdx.x * 128;
  const int lane = tid & 63;
  const int w = tid >> 6;
  const int wm = (w & 1) * 64, wn = (w >> 1) * 64;
  const int cr = (lane >> 4) * 4, cc = lane & 15;
  const f32x4 z4 = {0.f, 0.f, 0.f, 0.f};
  u32 target = 0;

  for (int s = s_begin; s < s_end; ++s) {
    const u16* A;
    u16* hout;
    const u16* xgs;
    if (seq_mode) {
      A    = hseq + (size_t)(s - 1) * 65536;
      hout = hseq + (size_t)s * 65536;
      xgs  = xg + (size_t)(s & 63) * 262144;
    } else {
      A    = ((s - 1) & 1) ? hb1 : hb0;
      hout = (s & 1) ? hb1 : hb0;
      xgs  = xg;
    }
    f32x4 acc[4][4];
    #pragma unroll
    for (int mt = 0; mt < 4; ++mt)
      #pragma unroll
      for (int nt = 0; nt < 4; ++nt) acc[mt][nt] = z4;

    gemm_core(A, B, 512, 0, n0, As, Bs, acc, tid);

    #pragma unroll
    for (int half = 0; half < 2; ++half) {
      __syncthreads();
      if (wm == half * 64) {
        #pragma unroll
        for (int mt = 0; mt < 4; ++mt)
          #pragma unroll
          for (int nt = 0; nt < 4; ++nt)
            #pragma unroll
            for (int ri = 0; ri < 4; ++ri)
              zb[(mt * 16 + cr + ri) * 128 + wn + nt * 16 + cc] = acc[mt][nt][ri];
      }
      __syncthreads();
      for (int c2 = tid; c2 < 2048; c2 += 256) {
        const int rl = c2 >> 5;
        const int q  = c2 & 31;
        const int m  = half * 64 + rl;
        const int jh = (n0 >> 2) + q;
        const long xr = seq_mode ? (long)m : (long)idx[(size_t)m * 512 + s];
        const ushort4 xq = *(const ushort4*)&xgs[xr * 2048 + n0 + q * 4];
        const float4 zv = *(const float4*)&zb[rl * 128 + q * 4];
        const float i_ = sigm(zv.x + bf(xq.x));
        const float f_ = sigm(zv.y + bf(xq.y));
        const float g_ = tanha(zv.z + bf(xq.z));
        const float o_ = sigm(zv.w + bf(xq.w));
        const size_t ci = (size_t)m * 512 + jh;
        const float cn = f_ * c_st[ci] + i_ * g_;
        c_st[ci] = cn;
        hout[(size_t)m * 512 + jh] = f2bf(o_ * tanha(cn));
      }
    }
    target += gridDim.x;
    if (s + 1 < s_end) gbar(cnt, target);
  }
}

// ---------------- persistent constituent LSTM (concat-K=1024), 16 blocks ----------------
__global__ __launch_bounds__(256) void k_seq_con(
    u16* hb0, u16* hb1, const u16* __restrict__ X /*red*/,
    const u16* __restrict__ B /*[Whh|Wih] K=1024*/, const float* __restrict__ bias,
    float* __restrict__ c_st, int s_begin, int s_end, u32* cnt)
{
  __shared__ u16 As[128 * LDST];
  __shared__ u16 Bs[128 * LDST];
  __shared__ float zb[64 * 128];
  const int tid = threadIdx.x;
  const int n0 = blockIdx.x * 128;
  const int lane = tid & 63;
  const int w = tid >> 6;
  const int wm = (w & 1) * 64, wn = (w >> 1) * 64;
  const int fr = lane & 15, fq = (lane >> 4) * 8;
  const int cr = (lane >> 4) * 4, cc = lane & 15;
  const f32x4 z4 = {0.f, 0.f, 0.f, 0.f};
  u32 target = 0;

  for (int s = s_begin; s < s_end; ++s) {
    const u16* H = ((s - 1) & 1) ? hb1 : hb0;
    u16* hout = (s & 1) ? hb1 : hb0;
    f32x4 acc[4][4];
    #pragma unroll
    for (int mt = 0; mt < 4; ++mt)
      #pragma unroll
      for (int nt = 0; nt < 4; ++nt) acc[mt][nt] = z4;

    for (int k0 = 0; k0 < 1024; k0 += 32) {
      __syncthreads();
      #pragma unroll
      for (int it = 0; it < 2; ++it) {
        const int l = tid + it * 256;
        const int r = l >> 2, kq = (l & 3) * 8;
        const u16* src = (k0 < 512)
            ? H + (size_t)r * 512 + k0 + kq
            : X + ((size_t)r * 128 + s) * 512 + (k0 - 512) + kq;
        *(uint4*)&As[r * LDST + kq] = *(const uint4*)src;
        *(uint4*)&Bs[r * LDST + kq] = *(const uint4*)&B[(size_t)(n0 + r) * 1024 + k0 + kq];
      }
      __syncthreads();
      short8 af[4], bfr[4];
      #pragma unroll
      for (int t = 0; t < 4; ++t) {
        af[t]  = *(const short8*)&As[(wm + t * 16 + fr) * LDST + fq];
        bfr[t] = *(const short8*)&Bs[(wn + t * 16 + fr) * LDST + fq];
      }
      #pragma unroll
      for (int mt = 0; mt < 4; ++mt)
        #pragma unroll
        for (int nt = 0; nt < 4; ++nt)
          acc[mt][nt] = __builtin_amdgcn_mfma_f32_16x16x32_bf16(af[mt], bfr[nt], acc[mt][nt], 0, 0, 0);
    }

    #pragma unroll
    for (int half = 0; half < 2; ++half) {
      __syncthreads();
      if (wm == half * 64) {
        #pragma unroll
        for (int mt = 0; mt < 4; ++mt)
          #pragma unroll
          for (int nt = 0; nt < 4; ++nt)
            #pragma unroll
            for (int ri = 0; ri < 4; ++ri)
              zb[(mt * 16 + cr + ri) * 128 + wn + nt * 16 + cc] = acc[mt][nt][ri];
      }
      __syncthreads();
      for (int c2 = tid; c2 < 2048; c2 += 256) {
        const int rl = c2 >> 5;
        const int q  = c2 & 31;
        const int m  = half * 64 + rl;
        const int jh = (n0 >> 2) + q;
        const float4 bv = *(const float4*)&bias[n0 + q * 4];
        const float4 zv = *(const float4*)&zb[rl * 128 + q * 4];
        const float i_ = sigm(zv.x + bv.x);
        const float f_ = sigm(zv.y + bv.y);
        const float g_ = tanha(zv.z + bv.z);
        const float o_ = sigm(zv.w + bv.w);
        const size_t ci = (size_t)m * 512 + jh;
        const float cn = f_ * c_st[ci] + i_ * g_;
        c_st[ci] = cn;
        hout[(size_t)m * 512 + jh] = f2bf(o_ * tanha(cn));
      }
    }
    target += gridDim.x;
    if (s + 1 < s_end) gbar(cnt, target);
  }
}

// ---------------- fused concat-K step (one step, many rows): reduce steps 2/3, con step0 ----------------
// cmode 1: xr=(2*(m&127)+p0)*128+(m>>7) [reduce children, X=c0]
// cmode 3: xr=m*128+p0                  [con, X=red]
// first=1: skip h half, c_old = 0
__global__ __launch_bounds__(256) void k_lstm_cat(
    const u16* __restrict__ H, const u16* __restrict__ X,
    const u16* __restrict__ B, const float* __restrict__ bias,
    const int* __restrict__ idx, int cmode, int p0, int first,
    float* __restrict__ c_st, u16* __restrict__ h_out, int h_stride, int h_coloff)
{
  __shared__ u16 As[128 * LDST];
  __shared__ u16 Bs[128 * LDST];
  __shared__ float zb[64 * 128];
  const int tid = threadIdx.x;
  const int m0 = blockIdx.x * 128, n0 = blockIdx.y * 128;
  const int lane = tid & 63;
  const int w = tid >> 6;
  const int wm = (w & 1) * 64, wn = (w >> 1) * 64;
  const int fr = lane & 15, fq = (lane >> 4) * 8;
  f32x4 acc[4][4];
  const f32x4 z4 = {0.f, 0.f, 0.f, 0.f};
  #pragma unroll
  for (int mt = 0; mt < 4; ++mt)
    #pragma unroll
    for (int nt = 0; nt < 4; ++nt) acc[mt][nt] = z4;

  for (int k0 = first ? 512 : 0; k0 < 1024; k0 += 32) {
    __syncthreads();
    #pragma unroll
    for (int it = 0; it < 2; ++it) {
      const int l = tid + it * 256;
      const int r = l >> 2, kq = (l & 3) * 8;
      const int m = m0 + r;
      const u16* src;
      if (k0 < 512) {
        src = H + (size_t)m * 512 + k0 + kq;
      } else {
        long xr;
        if (cmode == 1)      xr = (long)(2 * (m & 127) + p0) * 128 + (m >> 7);
        else if (cmode == 2) xr = (long)idx[m];
        else                 xr = (long)m * 128 + p0;
        src = X + (size_t)xr * 512 + (k0 - 512) + kq;
      }
      *(uint4*)&As[r * LDST + kq] = *(const uint4*)src;
      *(uint4*)&Bs[r * LDST + kq] = *(const uint4*)&B[(size_t)(n0 + r) * 1024 + k0 + kq];
    }
    __syncthreads();
    short8 af[4], bfr[4];
    #pragma unroll
    for (int t = 0; t < 4; ++t) {
      af[t]  = *(const short8*)&As[(wm + t * 16 + fr) * LDST + fq];
      bfr[t] = *(const short8*)&Bs[(wn + t * 16 + fr) * LDST + fq];
    }
    #pragma unroll
    for (int mt = 0; mt < 4; ++mt)
      #pragma unroll
      for (int nt = 0; nt < 4; ++nt)
        acc[mt][nt] = __builtin_amdgcn_mfma_f32_16x16x32_bf16(af[mt], bfr[nt], acc[mt][nt], 0, 0, 0);
  }

  const int cr = (lane >> 4) * 4, cc = lane & 15;
  #pragma unroll
  for (int half = 0; half < 2; ++half) {
    __syncthreads();
    if (wm == half * 64) {
      #pragma unroll
      for (int mt = 0; mt < 4; ++mt)
        #pragma unroll
        for (int nt = 0; nt < 4; ++nt)
          #pragma unroll
          for (int ri = 0; ri < 4; ++ri)
            zb[(mt * 16 + cr + ri) * 128 + wn + nt * 16 + cc] = acc[mt][nt][ri];
    }
    __syncthreads();
    for (int c = tid; c < 2048; c += 256) {
      const int rl = c >> 5;
      const int q  = c & 31;
      const int m  = m0 + half * 64 + rl;
      const int jh = (n0 >> 2) + q;
      const float4 bv = *(const float4*)&bias[n0 + q * 4];
      const float4 zv = *(const float4*)&zb[rl * 128 + q * 4];
      const float i_ = sigm(zv.x + bv.x);
      const float f_ = sigm(zv.y + bv.y);
      const float g_ = tanha(zv.z + bv.z);
      const float o_ = sigm(zv.w + bv.w);
      const size_t ci = (size_t)m * 512 + jh;
      const float cold = first ? 0.f : c_st[ci];
      const float cn = f_ * cold + i_ * g_;
      c_st[ci] = cn;
      h_out[(size_t)m * h_stride + h_coloff + jh] = f2bf(o_ * tanha(cn));
    }
  }
}

// ---------------- first LSTM step from XG table (no h) ----------------
__global__ __launch_bounds__(256) void k_gate0(
    const u16* __restrict__ xg, int xg_mode, int p0,
    const int* __restrict__ idx, int istride,
    float* __restrict__ c_st, u16* __restrict__ h_out, int h_stride, int h_coloff, int M)
{
  const int id = blockIdx.x * 256 + threadIdx.x;
  if (id >= M * 512) return;
  const int m = id >> 9, jh = id & 511;
  long xr;
  if (xg_mode == 0) xr = (long)m * p0;
  else              xr = (long)idx[(size_t)m * istride];
  const ushort4 xq = *(const ushort4*)&xg[xr * 2048 + jh * 4];
  const float i_ = sigm(bf(xq.x));
  const float g_ = tanha(bf(xq.z));
  const float o_ = sigm(bf(xq.w));
  const float cn = i_ * g_;
  c_st[(size_t)m * 512 + jh] = cn;
  h_out[(size_t)m * h_stride + h_coloff + jh] = f2bf(o_ * tanha(cn));
}

// ---------------- preps ----------------
__global__ void k_perm_w(const float* __restrict__ in, u16* __restrict__ out,
                         int Ksrc, int Kfill, int Ktot, int coff)
{
  const int rp = blockIdx.x;             // 0..2047
  const int g = rp & 3, jh = rp >> 2;
  const float* src = in + (size_t)(g * 512 + jh) * Ksrc;
  for (int k = threadIdx.x; k < Kfill; k += 256)
    out[(size_t)rp * Ktot + coff + k] = f2bf(k < Ksrc ? src[k] : 0.f);
}
__global__ void k_perm_b(const float* __restrict__ in, float* __restrict__ out)
{
  const int rp = blockIdx.x * 256 + threadIdx.x;
  out[rp] = in[(rp & 3) * 512 + (rp >> 2)];
}
__global__ void k_cvt(const float* __restrict__ in, u16* __restrict__ out, int n)
{
  const int i = blockIdx.x * 256 + threadIdx.x;
  if (i < n) out[i] = f2bf(in[i]);
}
__global__ void k_pad2d(const float* __restrict__ in, u16* __restrict__ out,
                        int Rin, int Kin, int Kout)
{
  const int r = blockIdx.x;
  for (int k = threadIdx.x; k < Kout; k += 256)
    out[(size_t)r * Kout + k] = f2bf((r < Rin && k < Kin) ? in[(size_t)r * Kin + k] : 0.f);
}
__global__ void k_gather_word(const int* __restrict__ widx, const int* __restrict__ tidx,
                              const float* __restrict__ emb, const float* __restrict__ temb,
                              u16* __restrict__ Aw)
{
  const int row = blockIdx.x;            // 0..32767 = s*128+b
  const int s = row >> 7, b = row & 127;
  const int wi = widx[b * kS + s];
  const int ti = tidx[b * kS + s];
  for (int t = threadIdx.x; t < 320; t += 256)
    Aw[(size_t)row * 320 + t] = f2bf(t < 300 ? emb[(size_t)wi * 300 + t] : temb[ti * 20 + t - 300]);
}

// ---------------- out = [word_h_last | tr_h | con_h] @ W^T + b ----------------
__global__ __launch_bounds__(256) void k_out(
    const u16* __restrict__ wh, const u16* __restrict__ trh, const u16* __restrict__ conh,
    const float* __restrict__ W, const float* __restrict__ bias, float* __restrict__ out)
{
  const int wid = blockIdx.x * 4 + (threadIdx.x >> 6);
  const int lane = threadIdx.x & 63;
  const int b = wid / kNT;
  const int t = wid - b * kNT;
  const u16* s0 = wh + (size_t)b * 512;
  const u16* s1 = trh + (size_t)b * 512;
  const u16* s2 = conh + (size_t)b * 512;
  const float* wr = W + (size_t)t * 1536;
  float acc = 0.f;
  #pragma unroll
  for (int i = 0; i < 8; ++i) acc += bf(s0[i * 64 + lane]) * wr[i * 64 + lane];
  #pragma unroll
  for (int i = 0; i < 8; ++i) acc += bf(s1[i * 64 + lane]) * wr[512 + i * 64 + lane];
  #pragma unroll
  for (int i = 0; i < 8; ++i) acc += bf(s2[i * 64 + lane]) * wr[1024 + i * 64 + lane];
  acc = wred(acc);
  if (lane == 0) out[(size_t)b * kNT + t] = acc + bias[t];
}

extern "C" void kernel_launch(void* const* d_in, const int* in_sizes, int n_in,
                              void* d_out, int out_size, void* d_ws, size_t ws_size,
                              hipStream_t stream)
{
  (void)in_sizes; (void)n_in; (void)out_size; (void)ws_size;
  const int* word_idx = (const int*)d_in[0];
  const int* tag_idx  = (const int*)d_in[1];
  const int* tr_idx   = (const int*)d_in[2];
  const int* lab_idx  = (const int*)d_in[3];
  const float* emb       = (const float*)d_in[4];
  const float* tag_emb   = (const float*)d_in[5];
  const float* tr_emb    = (const float*)d_in[6];
  const float* const_emb = (const float*)d_in[7];
  const float* word_Wih = (const float*)d_in[8];
  const float* word_Whh = (const float*)d_in[9];
  const float* word_b   = (const float*)d_in[10];
  const float* tr_Wih = (const float*)d_in[11];
  const float* tr_Whh = (const float*)d_in[12];
  const float* tr_b   = (const float*)d_in[13];
  const float* con_Wih = (const float*)d_in[14];
  const float* con_Whh = (const float*)d_in[15];
  const float* con_b   = (const float*)d_in[16];
  const float* fwd_Wih = (const float*)d_in[17];
  const float* fwd_Whh = (const float*)d_in[18];
  const float* fwd_b   = (const float*)d_in[19];
  const float* bwd_Wih = (const float*)d_in[20];
  const float* bwd_Whh = (const float*)d_in[21];
  const float* bwd_b   = (const float*)d_in[22];
  const float* w2c_W = (const float*)d_in[23];
  const float* w2c_b = (const float*)d_in[24];
  const float* red_W = (const float*)d_in[25];
  const float* red_b = (const float*)d_in[26];
  const float* out_W = (const float*)d_in[27];
  const float* out_b = (const float*)d_in[28];

  char* p = (char*)d_ws;
  auto alloc = [&](size_t bytes)->void* {
    void* r = (void*)p; p += (bytes + 255) & ~(size_t)255; return r;
  };
  // -------- arena (~195 MB; aliased lifetimes) --------
  u16* word_h = (u16*)alloc((size_t)32768*512*2);        // whole run
  char* R2    = (char*)alloc((size_t)32768*512*2);       // c0 / red
  char* R3    = (char*)alloc((size_t)16384*512*4);       // A_word / c_big
  char* R4    = (char*)alloc((size_t)16384*1024*2);      // XGbuf / fb
  u16* h1     = (u16*)alloc((size_t)16384*512*2);
  u16* h2     = (u16*)alloc((size_t)16384*512*2);
  u16* c0     = (u16*)R2;
  u16* red    = (u16*)R2;           // alias: c0 dead before red written
  u16* A_word = (u16*)R3;
  float* c_big= (float*)R3;         // alias: A_word dead before c_big written
  u16* XGbuf  = (u16*)R4;
  u16* fb     = (u16*)R4;           // alias: XGbuf dead before fb written
  // weights / small
  u16* wWih = (u16*)alloc((size_t)2048*320*2);
  u16* wWhh = (u16*)alloc((size_t)2048*512*2);
  u16* tWih = (u16*)alloc((size_t)2048*32*2);
  u16* tWhh = (u16*)alloc((size_t)2048*512*2);
  u16* cWcat = (u16*)alloc((size_t)2048*1024*2);
  u16* fWcat = (u16*)alloc((size_t)2048*1024*2);
  u16* bWcat = (u16*)alloc((size_t)2048*1024*2);
  u16* fWih  = (u16*)alloc((size_t)2048*512*2);
  u16* bWih  = (u16*)alloc((size_t)2048*512*2);
  u16* w2cWb = (u16*)alloc((size_t)512*512*2);
  u16* redWb = (u16*)alloc((size_t)512*1024*2);
  u16* A80   = (u16*)alloc((size_t)128*512*2);
  u16* Atr   = (u16*)alloc((size_t)128*32*2);
  u16* tbltr = (u16*)alloc((size_t)128*2048*2);
  u16* tbl0  = (u16*)alloc((size_t)128*2048*2);
  float* b_word = (float*)alloc(2048*4);
  float* b_tr   = (float*)alloc(2048*4);
  float* b_con  = (float*)alloc(2048*4);
  float* b_fwd  = (float*)alloc(2048*4);
  float* b_bwd  = (float*)alloc(2048*4);
  float* c_sm  = (float*)alloc((size_t)128*512*4);
  u16* trh1 = (u16*)alloc((size_t)128*512*2);
  u16* trh2 = (u16*)alloc((size_t)128*512*2);
  u16* ch1  = (u16*)alloc((size_t)128*512*2);
  u16* ch2  = (u16*)alloc((size_t)128*512*2);
  u32* counters = (u32*)alloc(8*4);

  // ---- init ----
  k_zero<<<1,256,0,stream>>>(counters, 8);

  // ---- preps ----
  k_perm_w<<<2048,256,0,stream>>>(word_Wih, wWih, 320, 320, 320, 0);
  k_perm_w<<<2048,256,0,stream>>>(word_Whh, wWhh, 512, 512, 512, 0);
  k_perm_w<<<2048,256,0,stream>>>(tr_Wih,   tWih, 20,  32,  32,  0);
  k_perm_w<<<2048,256,0,stream>>>(tr_Whh,   tWhh, 512, 512, 512, 0);
  k_perm_w<<<2048,256,0,stream>>>(con_Whh,  cWcat, 512, 512, 1024, 0);
  k_perm_w<<<2048,256,0,stream>>>(con_Wih,  cWcat, 512, 512, 1024, 512);
  k_perm_w<<<2048,256,0,stream>>>(fwd_Whh,  fWcat, 512, 512, 1024, 0);
  k_perm_w<<<2048,256,0,stream>>>(fwd_Wih,  fWcat, 512, 512, 1024, 512);
  k_perm_w<<<2048,256,0,stream>>>(bwd_Whh,  bWcat, 512, 512, 1024, 0);
  k_perm_w<<<2048,256,0,stream>>>(bwd_Wih,  bWcat, 512, 512, 1024, 512);
  k_perm_w<<<2048,256,0,stream>>>(fwd_Wih,  fWih, 512, 512, 512, 0);
  k_perm_w<<<2048,256,0,stream>>>(bwd_Wih,  bWih, 512, 512, 512, 0);
  k_perm_b<<<8,256,0,stream>>>(word_b, b_word);
  k_perm_b<<<8,256,0,stream>>>(tr_b,   b_tr);
  k_perm_b<<<8,256,0,stream>>>(con_b,  b_con);
  k_perm_b<<<8,256,0,stream>>>(fwd_b,  b_fwd);
  k_perm_b<<<8,256,0,stream>>>(bwd_b,  b_bwd);
  k_cvt<<<1024,256,0,stream>>>(w2c_W, w2cWb, 512*512);
  k_cvt<<<2048,256,0,stream>>>(red_W, redWb, 512*1024);
  k_pad2d<<<128,256,0,stream>>>(const_emb, A80, 80, 512, 512);
  k_pad2d<<<128,256,0,stream>>>(tr_emb,    Atr, 100, 20, 32);
  k_gather_word<<<32768,256,0,stream>>>(word_idx, tag_idx, emb, tag_emb, A_word);

  // ---- word LSTM: XG in 4 chunks of 64 steps + persistent seq kernels ----
  for (int c = 0; c < 4; ++c) {
    k_gemm<<<dim3(64,16),256,0,stream>>>(A_word + (size_t)c*8192*320, wWih, XGbuf,
                                         b_word, 320, 2048, 0);
    if (c == 0)
      k_gate0<<<256,256,0,stream>>>(XGbuf, 0, 1, nullptr, 0, c_sm, word_h, 512, 0, 128);
    const int s_begin = (c == 0) ? 1 : c*64;
    k_seq_lstm<<<16,256,0,stream>>>(word_h, nullptr, nullptr, wWhh, XGbuf, nullptr,
                                    c_sm, s_begin, c*64 + 64, 1, counters + c);
  }

  // ---- w2c: c0 = word_h @ w2c_W^T + b ----
  k_gemm<<<dim3(256,4),256,0,stream>>>(word_h, w2cWb, c0, w2c_b, 512, 512, 0);

  // ---- fwd reduce: table step1, concat-K steps 2-3 ----
  k_gemm<<<dim3(1,16),256,0,stream>>>(A80, fWih, tbl0, b_fwd, 512, 2048, 0);
  k_gate0<<<32768,256,0,stream>>>(tbl0, 2, 0, lab_idx, 1, c_big, h1, 512, 0, 16384);
  k_lstm_cat<<<dim3(128,16),256,0,stream>>>(h1, c0, fWcat, b_fwd, nullptr, 1, 0, 0, c_big, h2, 512, 0);
  k_lstm_cat<<<dim3(128,16),256,0,stream>>>(h2, c0, fWcat, b_fwd, nullptr, 1, 1, 0, c_big, fb, 1024, 0);
  // ---- bwd reduce ----
  k_gemm<<<dim3(1,16),256,0,stream>>>(A80, bWih, tbl0, b_bwd, 512, 2048, 0);
  k_gate0<<<32768,256,0,stream>>>(tbl0, 2, 0, lab_idx, 1, c_big, h1, 512, 0, 16384);
  k_lstm_cat<<<dim3(128,16),256,0,stream>>>(h1, c0, bWcat, b_bwd, nullptr, 1, 1, 0, c_big, h2, 512, 0);
  k_lstm_cat<<<dim3(128,16),256,0,stream>>>(h2, c0, bWcat, b_bwd, nullptr, 1, 0, 0, c_big, fb, 1024, 512);

  // ---- red = tanh([fh|bh] @ red_W^T + b) (c0 dead; red aliases it) ----
  k_gemm<<<dim3(128,4),256,0,stream>>>(fb, redWb, red, red_b, 1024, 512, 1);

  // ---- constituent LSTM: step0 + persistent (127 steps) ----
  k_lstm_cat<<<dim3(1,16),256,0,stream>>>(ch1, red, cWcat, b_con, nullptr, 3, 0, 1, c_sm, ch1, 512, 0);
  k_seq_con<<<16,256,0,stream>>>(ch1, ch2, red, cWcat, b_con, c_sm, 1, kR, counters + 4);
  u16* con_final = ch2;   // final step 127 (odd) -> ch2

  // ---- transition LSTM: table + step0 + persistent (511 steps) ----
  k_gemm<<<dim3(1,16),256,0,stream>>>(Atr, tWih, tbltr, b_tr, 32, 2048, 0);
  k_gate0<<<256,256,0,stream>>>(tbltr, 2, 0, tr_idx, 512, c_sm, trh1, 512, 0, 128);
  k_seq_lstm<<<16,256,0,stream>>>(nullptr, trh1, trh2, tWhh, tbltr, tr_idx,
                                  c_sm, 1, kT, 0, counters + 5);
  u16* tr_final = trh2;   // final step 511 (odd) -> trh2

  // ---- output ----
  k_out<<<3200,256,0,stream>>>(word_h + (size_t)255*128*512, tr_final, con_final,
                               out_W, out_b, (float*)d_out);
}

// Round 6
// 15387.657 us; speedup vs baseline: 3.5256x; 1.3529x over previous
//
#include <hip/hip_runtime.h>

typedef unsigned short u16;
typedef unsigned int u32;
typedef __attribute__((ext_vector_type(8))) short short8;
typedef __attribute__((ext_vector_type(4))) float f32x4;

namespace {
constexpr int kS  = 256;
constexpr int kT  = 512;
constexpr int kNT = 100;
constexpr int LDST = 40;   // LDS row stride (bf16) for 32-wide K chunks (cat/gemm kernels)
}

__device__ __forceinline__ float bf(u16 v){ return __uint_as_float(((u32)v)<<16); }
__device__ __forceinline__ u16 f2bf(float f){
  u32 u = __float_as_uint(f);
  return (u16)((u + 0x7fffu + ((u>>16)&1u)) >> 16);
}
__device__ __forceinline__ float sigm(float x){ return 1.f/(1.f+__expf(-x)); }
__device__ __forceinline__ float tanha(float x){ return 2.f/(1.f+__expf(-2.f*x)) - 1.f; }
__device__ __forceinline__ float wred(float v){
  #pragma unroll
  for (int off=32; off>0; off>>=1) v += __shfl_xor(v, off, 64);
  return v;
}

// device-scope sub-grid barrier (64 co-resident blocks per group)
__device__ __forceinline__ void gbar(u32* cnt, u32 target){
  __threadfence();
  __syncthreads();
  if (threadIdx.x == 0){
    __hip_atomic_fetch_add(cnt, 1u, __ATOMIC_RELEASE, __HIP_MEMORY_SCOPE_AGENT);
    while (__hip_atomic_load(cnt, __ATOMIC_ACQUIRE, __HIP_MEMORY_SCOPE_AGENT) < target)
      __builtin_amdgcn_s_sleep(1);
  }
  __syncthreads();
  __threadfence();
}

__global__ void k_zero(u32* p, int n){
  const int i = blockIdx.x*256 + threadIdx.x;
  if (i < n) p[i] = 0;
}

// ================= uniform persistent step kernel =================
// Each block owns 32 gate-cols (8 h-cols); Whh tile resident in LDS; c in LDS.
// mode 0 (word): A/out = hseq +/- step*65536, xg row = m (xg advanced by s*262144)
// mode 1 (tr):   A/out ping-pong hb0/hb1, xg row = idx[m*512+s]
// mode 2 (con):  ping-pong, xg row = m*128+s
struct SeqJob {
  u16* hseq; u16* hb0; u16* hb1;
  const u16* xg; const int* idx;
  float* c_io;
  const u16* Bw;     // permuted Whh [2048][512]
  u32* cnt;
  int s_begin, s_end, mode, c_store;
};

__global__ __launch_bounds__(256) void k_seq2(SeqJob jA, SeqJob jB)
{
  __shared__ u16 Bs[32*520];          // 33.3 KB resident weight tile
  __shared__ float c_lds[128*9];      // 4.6 KB block-private c columns
  __shared__ float sc[4*4*16*20];     // 20.5 KB wave-private epilogue scratch
  const SeqJob j = (blockIdx.x < 64) ? jA : jB;
  const int gb = blockIdx.x & 63;
  const int tid = threadIdx.x;
  const int ln = tid & 63, w = tid >> 6, wm = w * 32;
  const int fr = ln & 15, koff = (ln >> 4) * 8;
  const int n0 = gb * 32, jh0 = gb * 8;

  // load resident B tile (32 cols x 512 K) and c columns
  for (int e = tid; e < 2048; e += 256) {
    const int cl = e >> 6, kb = (e & 63) * 8;
    *(uint4*)&Bs[cl*520 + kb] = *(const uint4*)&j.Bw[(size_t)(n0+cl)*512 + kb];
  }
  for (int e = tid; e < 1024; e += 256) {
    const int m = e >> 3, jj = e & 7;
    c_lds[m*9 + jj] = j.c_io[(size_t)m*512 + jh0 + jj];
  }
  __syncthreads();

  u32 target = 0;
  const size_t aoff0 = (size_t)(wm + fr)*512 + koff;
  const size_t aoff1 = (size_t)(wm + 16 + fr)*512 + koff;
  const int cr = (ln>>4)*4, cc = ln&15;
  const int trow = ln>>2, jq = ln&3;
  const f32x4 z4 = {0.f,0.f,0.f,0.f};

  for (int s = j.s_begin; s < j.s_end; ++s) {
    const u16* Ab; u16* hout;
    if (j.mode == 0) { Ab = j.hseq + (size_t)(s-1)*65536; hout = j.hseq + (size_t)s*65536; }
    else { Ab = ((s-1)&1) ? j.hb1 : j.hb0; hout = (s&1) ? j.hb1 : j.hb0; }
    const u16* xgs = (j.mode == 0) ? (j.xg + (size_t)s*262144) : j.xg;

    f32x4 acc[2][2] = {{z4,z4},{z4,z4}};
    short8 a0 = *(const short8*)&Ab[aoff0];
    short8 a1 = *(const short8*)&Ab[aoff1];
    #pragma unroll
    for (int kt = 0; kt < 16; ++kt) {
      short8 n0a = a0, n1a = a1;
      if (kt < 15) {
        n0a = *(const short8*)&Ab[aoff0 + (size_t)(kt+1)*32];
        n1a = *(const short8*)&Ab[aoff1 + (size_t)(kt+1)*32];
      }
      const short8 b0 = *(const short8*)&Bs[fr*520 + kt*32 + koff];
      const short8 b1 = *(const short8*)&Bs[(16+fr)*520 + kt*32 + koff];
      acc[0][0] = __builtin_amdgcn_mfma_f32_16x16x32_bf16(a0, b0, acc[0][0], 0,0,0);
      acc[0][1] = __builtin_amdgcn_mfma_f32_16x16x32_bf16(a0, b1, acc[0][1], 0,0,0);
      acc[1][0] = __builtin_amdgcn_mfma_f32_16x16x32_bf16(a1, b0, acc[1][0], 0,0,0);
      acc[1][1] = __builtin_amdgcn_mfma_f32_16x16x32_bf16(a1, b1, acc[1][1], 0,0,0);
      a0 = n0a; a1 = n1a;
    }

    // epilogue: wave-private transpose via LDS, then gates
    #pragma unroll
    for (int mt=0; mt<2; ++mt)
      #pragma unroll
      for (int nt=0; nt<2; ++nt) {
        float* scb = &sc[(size_t)(w*4 + mt*2 + nt)*320];
        #pragma unroll
        for (int ri=0; ri<4; ++ri) scb[(cr+ri)*20 + cc] = acc[mt][nt][ri];
      }
    #pragma unroll
    for (int mt=0; mt<2; ++mt)
      #pragma unroll
      for (int nt=0; nt<2; ++nt) {
        const int m = wm + mt*16 + trow;
        const float4 zv = *(const float4*)&sc[(size_t)(w*4+mt*2+nt)*320 + trow*20 + 4*jq];
        long xr;
        if (j.mode == 0) xr = m;
        else if (j.mode == 1) xr = j.idx[(size_t)m*512 + s];
        else xr = (long)m*128 + s;
        const ushort4 xq = *(const ushort4*)&xgs[(size_t)xr*2048 + n0 + nt*16 + 4*jq];
        const float i_ = sigm(zv.x + bf(xq.x));
        const float f_ = sigm(zv.y + bf(xq.y));
        const float g_ = tanha(zv.z + bf(xq.z));
        const float o_ = sigm(zv.w + bf(xq.w));
        const int cj = m*9 + nt*4 + jq;
        const float cn = f_ * c_lds[cj] + i_ * g_;
        c_lds[cj] = cn;
        hout[(size_t)m*512 + jh0 + nt*4 + jq] = f2bf(o_ * tanha(cn));
      }
    target += 64;
    if (s + 1 < j.s_end) gbar(j.cnt, target);
  }
  if (j.c_store) {
    __syncthreads();
    for (int e = tid; e < 1024; e += 256) {
      const int m = e >> 3, jj = e & 7;
      j.c_io[(size_t)m*512 + jh0 + jj] = c_lds[m*9 + jj];
    }
  }
}

// ---------------- shared MFMA K-loop core (linear A): 128x128 C-tile, BK=32 ----------------
__device__ __forceinline__ void gemm_core(
    const u16* __restrict__ A, const u16* __restrict__ B, int K,
    int m0, int n0, u16* As, u16* Bs, f32x4 acc[4][4], int tid)
{
  const int lane = tid & 63;
  const int w = tid >> 6;
  const int wm = (w & 1) * 64, wn = (w >> 1) * 64;
  const int fr = lane & 15;
  const int fq = (lane >> 4) * 8;
  for (int k0 = 0; k0 < K; k0 += 32) {
    __syncthreads();
    #pragma unroll
    for (int it = 0; it < 2; ++it) {
      const int l = tid + it * 256;
      const int r = l >> 2, kq = (l & 3) * 8;
      *(uint4*)&As[r * LDST + kq] = *(const uint4*)&A[(size_t)(m0 + r) * K + k0 + kq];
      *(uint4*)&Bs[r * LDST + kq] = *(const uint4*)&B[(size_t)(n0 + r) * K + k0 + kq];
    }
    __syncthreads();
    short8 af[4], bfr[4];
    #pragma unroll
    for (int t = 0; t < 4; ++t) {
      af[t]  = *(const short8*)&As[(wm + t * 16 + fr) * LDST + fq];
      bfr[t] = *(const short8*)&Bs[(wn + t * 16 + fr) * LDST + fq];
    }
    #pragma unroll
    for (int mt = 0; mt < 4; ++mt)
      #pragma unroll
      for (int nt = 0; nt < 4; ++nt)
        acc[mt][nt] = __builtin_amdgcn_mfma_f32_16x16x32_bf16(af[mt], bfr[nt], acc[mt][nt], 0, 0, 0);
  }
}

// ---------------- plain GEMM: C = A @ B^T (+bias) (opt tanh), C bf16 ----------------
__global__ __launch_bounds__(256) void k_gemm(
    const u16* __restrict__ A, const u16* __restrict__ B, u16* __restrict__ C,
    const float* __restrict__ bias, int K, int N, int tanh_flag)
{
  __shared__ u16 As[128 * LDST];
  __shared__ u16 Bs[128 * LDST];
  const int tid = threadIdx.x;
  const int m0 = blockIdx.x * 128, n0 = blockIdx.y * 128;
  f32x4 acc[4][4];
  const f32x4 z4 = {0.f, 0.f, 0.f, 0.f};
  #pragma unroll
  for (int mt = 0; mt < 4; ++mt)
    #pragma unroll
    for (int nt = 0; nt < 4; ++nt) acc[mt][nt] = z4;

  gemm_core(A, B, K, m0, n0, As, Bs, acc, tid);

  const int lane = tid & 63;
  const int w = tid >> 6;
  const int wm = (w & 1) * 64, wn = (w >> 1) * 64;
  const int cr = (lane >> 4) * 4, cc = lane & 15;
  #pragma unroll
  for (int mt = 0; mt < 4; ++mt)
    #pragma unroll
    for (int nt = 0; nt < 4; ++nt)
      #pragma unroll
      for (int ri = 0; ri < 4; ++ri) {
        const int row = m0 + wm + mt * 16 + cr + ri;
        const int col = n0 + wn + nt * 16 + cc;
        float v = acc[mt][nt][ri];
        if (bias) v += bias[col];
        if (tanh_flag) v = tanha(v);
        C[(size_t)row * N + col] = f2bf(v);
      }
}

// ---------------- fused concat-K step (one step, many rows): reduce steps 2/3 ----------------
// cmode 1: xr=(2*(m&127)+p0)*128+(m>>7) [reduce children, X=c0]
__global__ __launch_bounds__(256) void k_lstm_cat(
    const u16* __restrict__ H, const u16* __restrict__ X,
    const u16* __restrict__ B, const float* __restrict__ bias,
    const int* __restrict__ idx, int cmode, int p0, int first,
    float* __restrict__ c_st, u16* __restrict__ h_out, int h_stride, int h_coloff)
{
  __shared__ u16 As[128 * LDST];
  __shared__ u16 Bs[128 * LDST];
  __shared__ float zb[64 * 128];
  const int tid = threadIdx.x;
  const int m0 = blockIdx.x * 128, n0 = blockIdx.y * 128;
  const int lane = tid & 63;
  const int w = tid >> 6;
  const int wm = (w & 1) * 64, wn = (w >> 1) * 64;
  const int fr = lane & 15, fq = (lane >> 4) * 8;
  f32x4 acc[4][4];
  const f32x4 z4 = {0.f, 0.f, 0.f, 0.f};
  #pragma unroll
  for (int mt = 0; mt < 4; ++mt)
    #pragma unroll
    for (int nt = 0; nt < 4; ++nt) acc[mt][nt] = z4;

  for (int k0 = first ? 512 : 0; k0 < 1024; k0 += 32) {
    __syncthreads();
    #pragma unroll
    for (int it = 0; it < 2; ++it) {
      const int l = tid + it * 256;
      const int r = l >> 2, kq = (l & 3) * 8;
      const int m = m0 + r;
      const u16* src;
      if (k0 < 512) {
        src = H + (size_t)m * 512 + k0 + kq;
      } else {
        long xr;
        if (cmode == 1)      xr = (long)(2 * (m & 127) + p0) * 128 + (m >> 7);
        else if (cmode == 2) xr = (long)idx[m];
        else                 xr = (long)m * 128 + p0;
        src = X + (size_t)xr * 512 + (k0 - 512) + kq;
      }
      *(uint4*)&As[r * LDST + kq] = *(const uint4*)src;
      *(uint4*)&Bs[r * LDST + kq] = *(const uint4*)&B[(size_t)(n0 + r) * 1024 + k0 + kq];
    }
    __syncthreads();
    short8 af[4], bfr[4];
    #pragma unroll
    for (int t = 0; t < 4; ++t) {
      af[t]  = *(const short8*)&As[(wm + t * 16 + fr) * LDST + fq];
      bfr[t] = *(const short8*)&Bs[(wn + t * 16 + fr) * LDST + fq];
    }
    #pragma unroll
    for (int mt = 0; mt < 4; ++mt)
      #pragma unroll
      for (int nt = 0; nt < 4; ++nt)
        acc[mt][nt] = __builtin_amdgcn_mfma_f32_16x16x32_bf16(af[mt], bfr[nt], acc[mt][nt], 0, 0, 0);
  }

  const int cr = (lane >> 4) * 4, cc = lane & 15;
  #pragma unroll
  for (int half = 0; half < 2; ++half) {
    __syncthreads();
    if (wm == half * 64) {
      #pragma unroll
      for (int mt = 0; mt < 4; ++mt)
        #pragma unroll
        for (int nt = 0; nt < 4; ++nt)
          #pragma unroll
          for (int ri = 0; ri < 4; ++ri)
            zb[(mt * 16 + cr + ri) * 128 + wn + nt * 16 + cc] = acc[mt][nt][ri];
    }
    __syncthreads();
    for (int c = tid; c < 2048; c += 256) {
      const int rl = c >> 5;
      const int q  = c & 31;
      const int m  = m0 + half * 64 + rl;
      const int jh = (n0 >> 2) + q;
      const float4 bv = *(const float4*)&bias[n0 + q * 4];
      const float4 zv = *(const float4*)&zb[rl * 128 + q * 4];
      const float i_ = sigm(zv.x + bv.x);
      const float f_ = sigm(zv.y + bv.y);
      const float g_ = tanha(zv.z + bv.z);
      const float o_ = sigm(zv.w + bv.w);
      const size_t ci = (size_t)m * 512 + jh;
      const float cold = first ? 0.f : c_st[ci];
      const float cn = f_ * cold + i_ * g_;
      c_st[ci] = cn;
      h_out[(size_t)m * h_stride + h_coloff + jh] = f2bf(o_ * tanha(cn));
    }
  }
}

// ---------------- first LSTM step from XG table (no h) ----------------
__global__ __launch_bounds__(256) void k_gate0(
    const u16* __restrict__ xg, int xg_mode, int p0,
    const int* __restrict__ idx, int istride,
    float* __restrict__ c_st, u16* __restrict__ h_out, int h_stride, int h_coloff, int M)
{
  const int id = blockIdx.x * 256 + threadIdx.x;
  if (id >= M * 512) return;
  const int m = id >> 9, jh = id & 511;
  long xr;
  if (xg_mode == 0) xr = (long)m * p0;
  else              xr = (long)idx[(size_t)m * istride];
  const ushort4 xq = *(const ushort4*)&xg[(size_t)xr * 2048 + jh * 4];
  const float i_ = sigm(bf(xq.x));
  const float g_ = tanha(bf(xq.z));
  const float o_ = sigm(bf(xq.w));
  const float cn = i_ * g_;
  c_st[(size_t)m * 512 + jh] = cn;
  h_out[(size_t)m * h_stride + h_coloff + jh] = f2bf(o_ * tanha(cn));
}

// ---------------- preps ----------------
__global__ void k_perm_w(const float* __restrict__ in, u16* __restrict__ out,
                         int Ksrc, int Kfill, int Ktot, int coff)
{
  const int rp = blockIdx.x;             // 0..2047
  const int g = rp & 3, jh = rp >> 2;
  const float* src = in + (size_t)(g * 512 + jh) * Ksrc;
  for (int k = threadIdx.x; k < Kfill; k += 256)
    out[(size_t)rp * Ktot + coff + k] = f2bf(k < Ksrc ? src[k] : 0.f);
}
__global__ void k_perm_b(const float* __restrict__ in, float* __restrict__ out)
{
  const int rp = blockIdx.x * 256 + threadIdx.x;
  out[rp] = in[(rp & 3) * 512 + (rp >> 2)];
}
__global__ void k_cvt(const float* __restrict__ in, u16* __restrict__ out, int n)
{
  const int i = blockIdx.x * 256 + threadIdx.x;
  if (i < n) out[i] = f2bf(in[i]);
}
__global__ void k_pad2d(const float* __restrict__ in, u16* __restrict__ out,
                        int Rin, int Kin, int Kout)
{
  const int r = blockIdx.x;
  for (int k = threadIdx.x; k < Kout; k += 256)
    out[(size_t)r * Kout + k] = f2bf((r < Rin && k < Kin) ? in[(size_t)r * Kin + k] : 0.f);
}
__global__ void k_gather_word(const int* __restrict__ widx, const int* __restrict__ tidx,
                              const float* __restrict__ emb, const float* __restrict__ temb,
                              u16* __restrict__ Aw)
{
  const int row = blockIdx.x;            // 0..32767 = s*128+b
  const int s = row >> 7, b = row & 127;
  const int wi = widx[b * kS + s];
  const int ti = tidx[b * kS + s];
  for (int t = threadIdx.x; t < 320; t += 256)
    Aw[(size_t)row * 320 + t] = f2bf(t < 300 ? emb[(size_t)wi * 300 + t] : temb[ti * 20 + t - 300]);
}

// ---------------- out = [word_h_last | tr_h | con_h] @ W^T + b ----------------
__global__ __launch_bounds__(256) void k_out(
    const u16* __restrict__ wh, const u16* __restrict__ trh, const u16* __restrict__ conh,
    const float* __restrict__ W, const float* __restrict__ bias, float* __restrict__ out)
{
  const int wid = blockIdx.x * 4 + (threadIdx.x >> 6);
  const int lane = threadIdx.x & 63;
  const int b = wid / kNT;
  const int t = wid - b * kNT;
  const u16* s0 = wh + (size_t)b * 512;
  const u16* s1 = trh + (size_t)b * 512;
  const u16* s2 = conh + (size_t)b * 512;
  const float* wr = W + (size_t)t * 1536;
  float acc = 0.f;
  #pragma unroll
  for (int i = 0; i < 8; ++i) acc += bf(s0[i * 64 + lane]) * wr[i * 64 + lane];
  #pragma unroll
  for (int i = 0; i < 8; ++i) acc += bf(s1[i * 64 + lane]) * wr[512 + i * 64 + lane];
  #pragma unroll
  for (int i = 0; i < 8; ++i) acc += bf(s2[i * 64 + lane]) * wr[1024 + i * 64 + lane];
  acc = wred(acc);
  if (lane == 0) out[(size_t)b * kNT + t] = acc + bias[t];
}

extern "C" void kernel_launch(void* const* d_in, const int* in_sizes, int n_in,
                              void* d_out, int out_size, void* d_ws, size_t ws_size,
                              hipStream_t stream)
{
  (void)in_sizes; (void)n_in; (void)out_size; (void)ws_size;
  const int* word_idx = (const int*)d_in[0];
  const int* tag_idx  = (const int*)d_in[1];
  const int* tr_idx   = (const int*)d_in[2];
  const int* lab_idx  = (const int*)d_in[3];
  const float* emb       = (const float*)d_in[4];
  const float* tag_emb   = (const float*)d_in[5];
  const float* tr_emb    = (const float*)d_in[6];
  const float* const_emb = (const float*)d_in[7];
  const float* word_Wih = (const float*)d_in[8];
  const float* word_Whh = (const float*)d_in[9];
  const float* word_b   = (const float*)d_in[10];
  const float* tr_Wih = (const float*)d_in[11];
  const float* tr_Whh = (const float*)d_in[12];
  const float* tr_b   = (const float*)d_in[13];
  const float* con_Wih = (const float*)d_in[14];
  const float* con_Whh = (const float*)d_in[15];
  const float* con_b   = (const float*)d_in[16];
  const float* fwd_Wih = (const float*)d_in[17];
  const float* fwd_Whh = (const float*)d_in[18];
  const float* fwd_b   = (const float*)d_in[19];
  const float* bwd_Wih = (const float*)d_in[20];
  const float* bwd_Whh = (const float*)d_in[21];
  const float* bwd_b   = (const float*)d_in[22];
  const float* w2c_W = (const float*)d_in[23];
  const float* w2c_b = (const float*)d_in[24];
  const float* red_W = (const float*)d_in[25];
  const float* red_b = (const float*)d_in[26];
  const float* out_W = (const float*)d_in[27];
  const float* out_b = (const float*)d_in[28];

  char* p = (char*)d_ws;
  auto alloc = [&](size_t bytes)->void* {
    void* r = (void*)p; p += (bytes + 255) & ~(size_t)255; return r;
  };
  // -------- arena (~215 MB; phase-aliased big region) --------
  u16* word_h = (u16*)alloc((size_t)32768*512*2);        // 33.55 MB, whole run
  char* R     = (char*)alloc((size_t)155189248);         // 155.2 MB aliased region
  u16* A_word = (u16*)(R);                               // prep phase (21.0 MB)
  u16* XGword = (u16*)(R + 20971520);                    // word phase (134.2 MB)
  u16* c0     = (u16*)(R);                               // reduce (33.55) - after XGword dead
  u16* h1     = (u16*)(R + 33554432);                    // 16.8
  u16* h2     = (u16*)(R + 50331648);                    // 16.8
  float* c_big= (float*)(R + 67108864);                  // 33.55
  u16* fb     = (u16*)(R + 100663296);                   // 33.55
  u16* red    = (u16*)(R + 134217728);                   // 16.8 (alive through con)
  u16* XG_con = (u16*)(R);                               // con phase (67.1) - reduce bufs dead
  // weights / small (persistent)
  u16* wWih = (u16*)alloc((size_t)2048*320*2);
  u16* wWhh = (u16*)alloc((size_t)2048*512*2);
  u16* tWih = (u16*)alloc((size_t)2048*32*2);
  u16* tWhh = (u16*)alloc((size_t)2048*512*2);
  u16* cWihp = (u16*)alloc((size_t)2048*512*2);
  u16* cWhhp = (u16*)alloc((size_t)2048*512*2);
  u16* fWcat = (u16*)alloc((size_t)2048*1024*2);
  u16* bWcat = (u16*)alloc((size_t)2048*1024*2);
  u16* fWih  = (u16*)alloc((size_t)2048*512*2);
  u16* bWih  = (u16*)alloc((size_t)2048*512*2);
  u16* w2cWb = (u16*)alloc((size_t)512*512*2);
  u16* redWb = (u16*)alloc((size_t)512*1024*2);
  u16* A80   = (u16*)alloc((size_t)128*512*2);
  u16* Atr   = (u16*)alloc((size_t)128*32*2);
  u16* tbltr = (u16*)alloc((size_t)128*2048*2);
  u16* tbl0  = (u16*)alloc((size_t)128*2048*2);
  float* b_word = (float*)alloc(2048*4);
  float* b_tr   = (float*)alloc(2048*4);
  float* b_con  = (float*)alloc(2048*4);
  float* b_fwd  = (float*)alloc(2048*4);
  float* b_bwd  = (float*)alloc(2048*4);
  float* c_word = (float*)alloc((size_t)128*512*4);
  float* c_tr   = (float*)alloc((size_t)128*512*4);
  float* c_con  = (float*)alloc((size_t)128*512*4);
  u16* trh1 = (u16*)alloc((size_t)128*512*2);
  u16* trh2 = (u16*)alloc((size_t)128*512*2);
  u16* ch1  = (u16*)alloc((size_t)128*512*2);
  u16* ch2  = (u16*)alloc((size_t)128*512*2);
  u32* counters = (u32*)alloc(16*4);

  // ---- init ----
  k_zero<<<1,256,0,stream>>>(counters, 16);

  // ---- preps ----
  k_perm_w<<<2048,256,0,stream>>>(word_Wih, wWih, 320, 320, 320, 0);
  k_perm_w<<<2048,256,0,stream>>>(word_Whh, wWhh, 512, 512, 512, 0);
  k_perm_w<<<2048,256,0,stream>>>(tr_Wih,   tWih, 20,  32,  32,  0);
  k_perm_w<<<2048,256,0,stream>>>(tr_Whh,   tWhh, 512, 512, 512, 0);
  k_perm_w<<<2048,256,0,stream>>>(con_Wih,  cWihp, 512, 512, 512, 0);
  k_perm_w<<<2048,256,0,stream>>>(con_Whh,  cWhhp, 512, 512, 512, 0);
  k_perm_w<<<2048,256,0,stream>>>(fwd_Whh,  fWcat, 512, 512, 1024, 0);
  k_perm_w<<<2048,256,0,stream>>>(fwd_Wih,  fWcat, 512, 512, 1024, 512);
  k_perm_w<<<2048,256,0,stream>>>(bwd_Whh,  bWcat, 512, 512, 1024, 0);
  k_perm_w<<<2048,256,0,stream>>>(bwd_Wih,  bWcat, 512, 512, 1024, 512);
  k_perm_w<<<2048,256,0,stream>>>(fwd_Wih,  fWih, 512, 512, 512, 0);
  k_perm_w<<<2048,256,0,stream>>>(bwd_Wih,  bWih, 512, 512, 512, 0);
  k_perm_b<<<8,256,0,stream>>>(word_b, b_word);
  k_perm_b<<<8,256,0,stream>>>(tr_b,   b_tr);
  k_perm_b<<<8,256,0,stream>>>(con_b,  b_con);
  k_perm_b<<<8,256,0,stream>>>(fwd_b,  b_fwd);
  k_perm_b<<<8,256,0,stream>>>(bwd_b,  b_bwd);
  k_cvt<<<1024,256,0,stream>>>(w2c_W, w2cWb, 512*512);
  k_cvt<<<2048,256,0,stream>>>(red_W, redWb, 512*1024);
  k_pad2d<<<128,256,0,stream>>>(const_emb, A80, 80, 512, 512);
  k_pad2d<<<128,256,0,stream>>>(tr_emb,    Atr, 100, 20, 32);
  k_gather_word<<<32768,256,0,stream>>>(word_idx, tag_idx, emb, tag_emb, A_word);

  // ---- XG tables ----
  k_gemm<<<dim3(256,16),256,0,stream>>>(A_word, wWih, XGword, b_word, 320, 2048, 0);
  k_gemm<<<dim3(1,16),256,0,stream>>>(Atr, tWih, tbltr, b_tr, 32, 2048, 0);

  // ---- step 0 for word and transition ----
  k_gate0<<<256,256,0,stream>>>(XGword, 0, 1, nullptr, 0, c_word, word_h, 512, 0, 128);
  k_gate0<<<256,256,0,stream>>>(tbltr, 2, 0, tr_idx, 512, c_tr, trh1, 512, 0, 128);

  // ---- launch 1: word(1..255) || transition(1..255) ----
  SeqJob jw{ word_h, nullptr, nullptr, XGword, nullptr, c_word, wWhh, counters+0, 1, 256, 0, 0 };
  SeqJob jt1{ nullptr, trh1, trh2, tbltr, tr_idx, c_tr, tWhh, counters+1, 1, 256, 1, 1 };
  k_seq2<<<128,256,0,stream>>>(jw, jt1);

  // ---- w2c: c0 = word_h @ w2c_W^T + b ----
  k_gemm<<<dim3(256,4),256,0,stream>>>(word_h, w2cWb, c0, w2c_b, 512, 512, 0);

  // ---- fwd reduce ----
  k_gemm<<<dim3(1,16),256,0,stream>>>(A80, fWih, tbl0, b_fwd, 512, 2048, 0);
  k_gate0<<<32768,256,0,stream>>>(tbl0, 2, 0, lab_idx, 1, c_big, h1, 512, 0, 16384);
  k_lstm_cat<<<dim3(128,16),256,0,stream>>>(h1, c0, fWcat, b_fwd, nullptr, 1, 0, 0, c_big, h2, 512, 0);
  k_lstm_cat<<<dim3(128,16),256,0,stream>>>(h2, c0, fWcat, b_fwd, nullptr, 1, 1, 0, c_big, fb, 1024, 0);
  // ---- bwd reduce ----
  k_gemm<<<dim3(1,16),256,0,stream>>>(A80, bWih, tbl0, b_bwd, 512, 2048, 0);
  k_gate0<<<32768,256,0,stream>>>(tbl0, 2, 0, lab_idx, 1, c_big, h1, 512, 0, 16384);
  k_lstm_cat<<<dim3(128,16),256,0,stream>>>(h1, c0, bWcat, b_bwd, nullptr, 1, 1, 0, c_big, h2, 512, 0);
  k_lstm_cat<<<dim3(128,16),256,0,stream>>>(h2, c0, bWcat, b_bwd, nullptr, 1, 0, 0, c_big, fb, 1024, 512);

  // ---- red = tanh([fh|bh] @ red_W^T + b) ----
  k_gemm<<<dim3(128,4),256,0,stream>>>(fb, redWb, red, red_b, 1024, 512, 1);

  // ---- XG_con = red @ con_Wih^T + b_con (reduce buffers dead) ----
  k_gemm<<<dim3(128,16),256,0,stream>>>(red, cWihp, XG_con, b_con, 512, 2048, 0);

  // ---- con step 0 ----
  k_gate0<<<256,256,0,stream>>>(XG_con, 0, 128, nullptr, 0, c_con, ch1, 512, 0, 128);

  // ---- launch 2: con(1..127) || transition(256..511) ----
  SeqJob jc{ nullptr, ch1, ch2, XG_con, nullptr, c_con, cWhhp, counters+2, 1, 128, 2, 0 };
  SeqJob jt2{ nullptr, trh1, trh2, tbltr, tr_idx, c_tr, tWhh, counters+3, 256, 512, 1, 0 };
  k_seq2<<<128,256,0,stream>>>(jc, jt2);

  // ---- output ----
  k_out<<<3200,256,0,stream>>>(word_h + (size_t)255*128*512, trh2, ch2,
                               out_W, out_b, (float*)d_out);
}

// Round 7
// 14545.872 us; speedup vs baseline: 3.7296x; 1.0579x over previous
//
#include <hip/hip_runtime.h>

typedef unsigned short u16;
typedef unsigned int u32;
typedef __attribute__((ext_vector_type(8))) short short8;
typedef __attribute__((ext_vector_type(4))) float f32x4;

namespace {
constexpr int kS  = 256;
constexpr int kT  = 512;
constexpr int kNT = 100;
constexpr int LDST = 40;   // LDS row stride (bf16) for 32-wide K chunks (cat/gemm kernels)
}

__device__ __forceinline__ float bf(u16 v){ return __uint_as_float(((u32)v)<<16); }
__device__ __forceinline__ u16 f2bf(float f){
  u32 u = __float_as_uint(f);
  return (u16)((u + 0x7fffu + ((u>>16)&1u)) >> 16);
}
__device__ __forceinline__ float sigm(float x){ return 1.f/(1.f+__expf(-x)); }
__device__ __forceinline__ float tanha(float x){ return 2.f/(1.f+__expf(-2.f*x)) - 1.f; }
__device__ __forceinline__ float wred(float v){
  #pragma unroll
  for (int off=32; off>0; off>>=1) v += __shfl_xor(v, off, 64);
  return v;
}

__global__ void k_zero(u32* p, int n){
  const int i = blockIdx.x*256 + threadIdx.x;
  if (i < n) p[i] = 0;
}

// ================= uniform persistent step kernel =================
// Each block owns 32 gate-cols (8 h-cols); Whh tile resident in LDS; c in LDS.
// mode 0 (word): A/out = hseq + step*65536, xg row = m (xg advanced by s*262144)
// mode 1 (tr):   A/out ping-pong hb0/hb1, xg row = idx[m*512+s]
// mode 2 (con):  ping-pong, xg row = m*128+s
// Sync: distributed flag array — block gb release-stores step s to flags[gb*32];
// wave 0 polls all 64 flags in parallel (no RMW contention).
struct SeqJob {
  u16* hseq; u16* hb0; u16* hb1;
  const u16* xg; const int* idx;
  float* c_io;
  const u16* Bw;     // permuted Whh [2048][512]
  u32* flags;        // 64 flags, 32-u32 padded (one cacheline each)
  int s_begin, s_end, mode, c_store;
};

__global__ __launch_bounds__(256) void k_seq2(SeqJob jA, SeqJob jB)
{
  __shared__ u16 Bs[32*520];          // 33.3 KB resident weight tile
  __shared__ float c_lds[128*9];      // 4.6 KB block-private c columns
  __shared__ float sc[4*4*16*20];     // 20.5 KB wave-private epilogue scratch
  const SeqJob j = (blockIdx.x < 64) ? jA : jB;
  const int gb = blockIdx.x & 63;
  const int tid = threadIdx.x;
  const int ln = tid & 63, w = tid >> 6, wm = w * 32;
  const int fr = ln & 15, koff = (ln >> 4) * 8;
  const int n0 = gb * 32, jh0 = gb * 8;

  // load resident B tile (32 cols x 512 K) and c columns
  for (int e = tid; e < 2048; e += 256) {
    const int cl = e >> 6, kb = (e & 63) * 8;
    *(uint4*)&Bs[cl*520 + kb] = *(const uint4*)&j.Bw[(size_t)(n0+cl)*512 + kb];
  }
  for (int e = tid; e < 1024; e += 256) {
    const int m = e >> 3, jj = e & 7;
    c_lds[m*9 + jj] = j.c_io[(size_t)m*512 + jh0 + jj];
  }
  __syncthreads();

  const size_t aoff0 = (size_t)(wm + fr)*512 + koff;
  const size_t aoff1 = (size_t)(wm + 16 + fr)*512 + koff;
  const int cr = (ln>>4)*4, cc = ln&15;
  const int trow = ln>>2, jq = ln&3;
  const f32x4 z4 = {0.f,0.f,0.f,0.f};

  for (int s = j.s_begin; s < j.s_end; ++s) {
    const u16* Ab; u16* hout;
    if (j.mode == 0) { Ab = j.hseq + (size_t)(s-1)*65536; hout = j.hseq + (size_t)s*65536; }
    else { Ab = ((s-1)&1) ? j.hb1 : j.hb0; hout = (s&1) ? j.hb1 : j.hb0; }
    const u16* xgs = (j.mode == 0) ? (j.xg + (size_t)s*262144) : j.xg;

    f32x4 acc[2][2] = {{z4,z4},{z4,z4}};
    short8 a0 = *(const short8*)&Ab[aoff0];
    short8 a1 = *(const short8*)&Ab[aoff1];
    #pragma unroll
    for (int kt = 0; kt < 16; ++kt) {
      short8 n0a = a0, n1a = a1;
      if (kt < 15) {
        n0a = *(const short8*)&Ab[aoff0 + (size_t)(kt+1)*32];
        n1a = *(const short8*)&Ab[aoff1 + (size_t)(kt+1)*32];
      }
      const short8 b0 = *(const short8*)&Bs[fr*520 + kt*32 + koff];
      const short8 b1 = *(const short8*)&Bs[(16+fr)*520 + kt*32 + koff];
      acc[0][0] = __builtin_amdgcn_mfma_f32_16x16x32_bf16(a0, b0, acc[0][0], 0,0,0);
      acc[0][1] = __builtin_amdgcn_mfma_f32_16x16x32_bf16(a0, b1, acc[0][1], 0,0,0);
      acc[1][0] = __builtin_amdgcn_mfma_f32_16x16x32_bf16(a1, b0, acc[1][0], 0,0,0);
      acc[1][1] = __builtin_amdgcn_mfma_f32_16x16x32_bf16(a1, b1, acc[1][1], 0,0,0);
      a0 = n0a; a1 = n1a;
    }

    // epilogue: wave-private transpose via LDS, then gates
    #pragma unroll
    for (int mt=0; mt<2; ++mt)
      #pragma unroll
      for (int nt=0; nt<2; ++nt) {
        float* scb = &sc[(size_t)(w*4 + mt*2 + nt)*320];
        #pragma unroll
        for (int ri=0; ri<4; ++ri) scb[(cr+ri)*20 + cc] = acc[mt][nt][ri];
      }
    #pragma unroll
    for (int mt=0; mt<2; ++mt)
      #pragma unroll
      for (int nt=0; nt<2; ++nt) {
        const int m = wm + mt*16 + trow;
        const float4 zv = *(const float4*)&sc[(size_t)(w*4+mt*2+nt)*320 + trow*20 + 4*jq];
        long xr;
        if (j.mode == 0) xr = m;
        else if (j.mode == 1) xr = j.idx[(size_t)m*512 + s];
        else xr = (long)m*128 + s;
        const ushort4 xq = *(const ushort4*)&xgs[(size_t)xr*2048 + n0 + nt*16 + 4*jq];
        const float i_ = sigm(zv.x + bf(xq.x));
        const float f_ = sigm(zv.y + bf(xq.y));
        const float g_ = tanha(zv.z + bf(xq.z));
        const float o_ = sigm(zv.w + bf(xq.w));
        const int cj = m*9 + nt*4 + jq;
        const float cn = f_ * c_lds[cj] + i_ * g_;
        c_lds[cj] = cn;
        hout[(size_t)m*512 + jh0 + nt*4 + jq] = f2bf(o_ * tanha(cn));
      }

    // ---- distributed-flag sync ----
    __threadfence();                 // drain h stores to agent scope
    __syncthreads();
    if (tid == 0)
      __hip_atomic_store(j.flags + (gb << 5), (u32)s, __ATOMIC_RELEASE, __HIP_MEMORY_SCOPE_AGENT);
    if (s + 1 < j.s_end) {
      if (tid < 64) {
        while (true) {
          u32 f = __hip_atomic_load(j.flags + (tid << 5), __ATOMIC_RELAXED, __HIP_MEMORY_SCOPE_AGENT);
          if (__all(f >= (u32)s)) break;
          __builtin_amdgcn_s_sleep(1);
        }
      }
      __syncthreads();
      __threadfence();               // acquire: invalidate stale h lines
    }
  }
  if (j.c_store) {
    __syncthreads();
    for (int e = tid; e < 1024; e += 256) {
      const int m = e >> 3, jj = e & 7;
      j.c_io[(size_t)m*512 + jh0 + jj] = c_lds[m*9 + jj];
    }
  }
}

// ---------------- shared MFMA K-loop core (linear A): 128x128 C-tile, BK=32 ----------------
__device__ __forceinline__ void gemm_core(
    const u16* __restrict__ A, const u16* __restrict__ B, int K,
    int m0, int n0, u16* As, u16* Bs, f32x4 acc[4][4], int tid)
{
  const int lane = tid & 63;
  const int w = tid >> 6;
  const int wm = (w & 1) * 64, wn = (w >> 1) * 64;
  const int fr = lane & 15;
  const int fq = (lane >> 4) * 8;
  for (int k0 = 0; k0 < K; k0 += 32) {
    __syncthreads();
    #pragma unroll
    for (int it = 0; it < 2; ++it) {
      const int l = tid + it * 256;
      const int r = l >> 2, kq = (l & 3) * 8;
      *(uint4*)&As[r * LDST + kq] = *(const uint4*)&A[(size_t)(m0 + r) * K + k0 + kq];
      *(uint4*)&Bs[r * LDST + kq] = *(const uint4*)&B[(size_t)(n0 + r) * K + k0 + kq];
    }
    __syncthreads();
    short8 af[4], bfr[4];
    #pragma unroll
    for (int t = 0; t < 4; ++t) {
      af[t]  = *(const short8*)&As[(wm + t * 16 + fr) * LDST + fq];
      bfr[t] = *(const short8*)&Bs[(wn + t * 16 + fr) * LDST + fq];
    }
    #pragma unroll
    for (int mt = 0; mt < 4; ++mt)
      #pragma unroll
      for (int nt = 0; nt < 4; ++nt)
        acc[mt][nt] = __builtin_amdgcn_mfma_f32_16x16x32_bf16(af[mt], bfr[nt], acc[mt][nt], 0, 0, 0);
  }
}

// ---------------- plain GEMM: C = A @ B^T (+bias) (opt tanh), C bf16 ----------------
__global__ __launch_bounds__(256) void k_gemm(
    const u16* __restrict__ A, const u16* __restrict__ B, u16* __restrict__ C,
    const float* __restrict__ bias, int K, int N, int tanh_flag)
{
  __shared__ u16 As[128 * LDST];
  __shared__ u16 Bs[128 * LDST];
  const int tid = threadIdx.x;
  const int m0 = blockIdx.x * 128, n0 = blockIdx.y * 128;
  f32x4 acc[4][4];
  const f32x4 z4 = {0.f, 0.f, 0.f, 0.f};
  #pragma unroll
  for (int mt = 0; mt < 4; ++mt)
    #pragma unroll
    for (int nt = 0; nt < 4; ++nt) acc[mt][nt] = z4;

  gemm_core(A, B, K, m0, n0, As, Bs, acc, tid);

  const int lane = tid & 63;
  const int w = tid >> 6;
  const int wm = (w & 1) * 64, wn = (w >> 1) * 64;
  const int cr = (lane >> 4) * 4, cc = lane & 15;
  #pragma unroll
  for (int mt = 0; mt < 4; ++mt)
    #pragma unroll
    for (int nt = 0; nt < 4; ++nt)
      #pragma unroll
      for (int ri = 0; ri < 4; ++ri) {
        const int row = m0 + wm + mt * 16 + cr + ri;
        const int col = n0 + wn + nt * 16 + cc;
        float v = acc[mt][nt][ri];
        if (bias) v += bias[col];
        if (tanh_flag) v = tanha(v);
        C[(size_t)row * N + col] = f2bf(v);
      }
}

// ---------------- fused concat-K step (one step, many rows): reduce steps 2/3 ----------------
// cmode 1: xr=(2*(m&127)+p0)*128+(m>>7) [reduce children, X=c0]
__global__ __launch_bounds__(256) void k_lstm_cat(
    const u16* __restrict__ H, const u16* __restrict__ X,
    const u16* __restrict__ B, const float* __restrict__ bias,
    const int* __restrict__ idx, int cmode, int p0, int first,
    float* __restrict__ c_st, u16* __restrict__ h_out, int h_stride, int h_coloff)
{
  __shared__ u16 As[128 * LDST];
  __shared__ u16 Bs[128 * LDST];
  __shared__ float zb[64 * 128];
  const int tid = threadIdx.x;
  const int m0 = blockIdx.x * 128, n0 = blockIdx.y * 128;
  const int lane = tid & 63;
  const int w = tid >> 6;
  const int wm = (w & 1) * 64, wn = (w >> 1) * 64;
  const int fr = lane & 15, fq = (lane >> 4) * 8;
  f32x4 acc[4][4];
  const f32x4 z4 = {0.f, 0.f, 0.f, 0.f};
  #pragma unroll
  for (int mt = 0; mt < 4; ++mt)
    #pragma unroll
    for (int nt = 0; nt < 4; ++nt) acc[mt][nt] = z4;

  for (int k0 = first ? 512 : 0; k0 < 1024; k0 += 32) {
    __syncthreads();
    #pragma unroll
    for (int it = 0; it < 2; ++it) {
      const int l = tid + it * 256;
      const int r = l >> 2, kq = (l & 3) * 8;
      const int m = m0 + r;
      const u16* src;
      if (k0 < 512) {
        src = H + (size_t)m * 512 + k0 + kq;
      } else {
        long xr;
        if (cmode == 1)      xr = (long)(2 * (m & 127) + p0) * 128 + (m >> 7);
        else if (cmode == 2) xr = (long)idx[m];
        else                 xr = (long)m * 128 + p0;
        src = X + (size_t)xr * 512 + (k0 - 512) + kq;
      }
      *(uint4*)&As[r * LDST + kq] = *(const uint4*)src;
      *(uint4*)&Bs[r * LDST + kq] = *(const uint4*)&B[(size_t)(n0 + r) * 1024 + k0 + kq];
    }
    __syncthreads();
    short8 af[4], bfr[4];
    #pragma unroll
    for (int t = 0; t < 4; ++t) {
      af[t]  = *(const short8*)&As[(wm + t * 16 + fr) * LDST + fq];
      bfr[t] = *(const short8*)&Bs[(wn + t * 16 + fr) * LDST + fq];
    }
    #pragma unroll
    for (int mt = 0; mt < 4; ++mt)
      #pragma unroll
      for (int nt = 0; nt < 4; ++nt)
        acc[mt][nt] = __builtin_amdgcn_mfma_f32_16x16x32_bf16(af[mt], bfr[nt], acc[mt][nt], 0, 0, 0);
  }

  const int cr = (lane >> 4) * 4, cc = lane & 15;
  #pragma unroll
  for (int half = 0; half < 2; ++half) {
    __syncthreads();
    if (wm == half * 64) {
      #pragma unroll
      for (int mt = 0; mt < 4; ++mt)
        #pragma unroll
        for (int nt = 0; nt < 4; ++nt)
          #pragma unroll
          for (int ri = 0; ri < 4; ++ri)
            zb[(mt * 16 + cr + ri) * 128 + wn + nt * 16 + cc] = acc[mt][nt][ri];
    }
    __syncthreads();
    for (int c = tid; c < 2048; c += 256) {
      const int rl = c >> 5;
      const int q  = c & 31;
      const int m  = m0 + half * 64 + rl;
      const int jh = (n0 >> 2) + q;
      const float4 bv = *(const float4*)&bias[n0 + q * 4];
      const float4 zv = *(const float4*)&zb[rl * 128 + q * 4];
      const float i_ = sigm(zv.x + bv.x);
      const float f_ = sigm(zv.y + bv.y);
      const float g_ = tanha(zv.z + bv.z);
      const float o_ = sigm(zv.w + bv.w);
      const size_t ci = (size_t)m * 512 + jh;
      const float cold = first ? 0.f : c_st[ci];
      const float cn = f_ * cold + i_ * g_;
      c_st[ci] = cn;
      h_out[(size_t)m * h_stride + h_coloff + jh] = f2bf(o_ * tanha(cn));
    }
  }
}

// ---------------- first LSTM step from XG table (no h) ----------------
__global__ __launch_bounds__(256) void k_gate0(
    const u16* __restrict__ xg, int xg_mode, int p0,
    const int* __restrict__ idx, int istride,
    float* __restrict__ c_st, u16* __restrict__ h_out, int h_stride, int h_coloff, int M)
{
  const int id = blockIdx.x * 256 + threadIdx.x;
  if (id >= M * 512) return;
  const int m = id >> 9, jh = id & 511;
  long xr;
  if (xg_mode == 0) xr = (long)m * p0;
  else              xr = (long)idx[(size_t)m * istride];
  const ushort4 xq = *(const ushort4*)&xg[(size_t)xr * 2048 + jh * 4];
  const float i_ = sigm(bf(xq.x));
  const float g_ = tanha(bf(xq.z));
  const float o_ = sigm(bf(xq.w));
  const float cn = i_ * g_;
  c_st[(size_t)m * 512 + jh] = cn;
  h_out[(size_t)m * h_stride + h_coloff + jh] = f2bf(o_ * tanha(cn));
}

// ---------------- preps ----------------
__global__ void k_perm_w(const float* __restrict__ in, u16* __restrict__ out,
                         int Ksrc, int Kfill, int Ktot, int coff)
{
  const int rp = blockIdx.x;             // 0..2047
  const int g = rp & 3, jh = rp >> 2;
  const float* src = in + (size_t)(g * 512 + jh) * Ksrc;
  for (int k = threadIdx.x; k < Kfill; k += 256)
    out[(size_t)rp * Ktot + coff + k] = f2bf(k < Ksrc ? src[k] : 0.f);
}
__global__ void k_perm_b(const float* __restrict__ in, float* __restrict__ out)
{
  const int rp = blockIdx.x * 256 + threadIdx.x;
  out[rp] = in[(rp & 3) * 512 + (rp >> 2)];
}
__global__ void k_cvt(const float* __restrict__ in, u16* __restrict__ out, int n)
{
  const int i = blockIdx.x * 256 + threadIdx.x;
  if (i < n) out[i] = f2bf(in[i]);
}
__global__ void k_pad2d(const float* __restrict__ in, u16* __restrict__ out,
                        int Rin, int Kin, int Kout)
{
  const int r = blockIdx.x;
  for (int k = threadIdx.x; k < Kout; k += 256)
    out[(size_t)r * Kout + k] = f2bf((r < Rin && k < Kin) ? in[(size_t)r * Kin + k] : 0.f);
}
__global__ void k_gather_word(const int* __restrict__ widx, const int* __restrict__ tidx,
                              const float* __restrict__ emb, const float* __restrict__ temb,
                              u16* __restrict__ Aw)
{
  const int row = blockIdx.x;            // 0..32767 = s*128+b
  const int s = row >> 7, b = row & 127;
  const int wi = widx[b * kS + s];
  const int ti = tidx[b * kS + s];
  for (int t = threadIdx.x; t < 320; t += 256)
    Aw[(size_t)row * 320 + t] = f2bf(t < 300 ? emb[(size_t)wi * 300 + t] : temb[ti * 20 + t - 300]);
}

// ---------------- out = [word_h_last | tr_h | con_h] @ W^T + b ----------------
__global__ __launch_bounds__(256) void k_out(
    const u16* __restrict__ wh, const u16* __restrict__ trh, const u16* __restrict__ conh,
    const float* __restrict__ W, const float* __restrict__ bias, float* __restrict__ out)
{
  const int wid = blockIdx.x * 4 + (threadIdx.x >> 6);
  const int lane = threadIdx.x & 63;
  const int b = wid / kNT;
  const int t = wid - b * kNT;
  const u16* s0 = wh + (size_t)b * 512;
  const u16* s1 = trh + (size_t)b * 512;
  const u16* s2 = conh + (size_t)b * 512;
  const float* wr = W + (size_t)t * 1536;
  float acc = 0.f;
  #pragma unroll
  for (int i = 0; i < 8; ++i) acc += bf(s0[i * 64 + lane]) * wr[i * 64 + lane];
  #pragma unroll
  for (int i = 0; i < 8; ++i) acc += bf(s1[i * 64 + lane]) * wr[512 + i * 64 + lane];
  #pragma unroll
  for (int i = 0; i < 8; ++i) acc += bf(s2[i * 64 + lane]) * wr[1024 + i * 64 + lane];
  acc = wred(acc);
  if (lane == 0) out[(size_t)b * kNT + t] = acc + bias[t];
}

extern "C" void kernel_launch(void* const* d_in, const int* in_sizes, int n_in,
                              void* d_out, int out_size, void* d_ws, size_t ws_size,
                              hipStream_t stream)
{
  (void)in_sizes; (void)n_in; (void)out_size; (void)ws_size;
  const int* word_idx = (const int*)d_in[0];
  const int* tag_idx  = (const int*)d_in[1];
  const int* tr_idx   = (const int*)d_in[2];
  const int* lab_idx  = (const int*)d_in[3];
  const float* emb       = (const float*)d_in[4];
  const float* tag_emb   = (const float*)d_in[5];
  const float* tr_emb    = (const float*)d_in[6];
  const float* const_emb = (const float*)d_in[7];
  const float* word_Wih = (const float*)d_in[8];
  const float* word_Whh = (const float*)d_in[9];
  const float* word_b   = (const float*)d_in[10];
  const float* tr_Wih = (const float*)d_in[11];
  const float* tr_Whh = (const float*)d_in[12];
  const float* tr_b   = (const float*)d_in[13];
  const float* con_Wih = (const float*)d_in[14];
  const float* con_Whh = (const float*)d_in[15];
  const float* con_b   = (const float*)d_in[16];
  const float* fwd_Wih = (const float*)d_in[17];
  const float* fwd_Whh = (const float*)d_in[18];
  const float* fwd_b   = (const float*)d_in[19];
  const float* bwd_Wih = (const float*)d_in[20];
  const float* bwd_Whh = (const float*)d_in[21];
  const float* bwd_b   = (const float*)d_in[22];
  const float* w2c_W = (const float*)d_in[23];
  const float* w2c_b = (const float*)d_in[24];
  const float* red_W = (const float*)d_in[25];
  const float* red_b = (const float*)d_in[26];
  const float* out_W = (const float*)d_in[27];
  const float* out_b = (const float*)d_in[28];

  char* p = (char*)d_ws;
  auto alloc = [&](size_t bytes)->void* {
    void* r = (void*)p; p += (bytes + 255) & ~(size_t)255; return r;
  };
  // -------- arena (~215 MB; phase-aliased big region) --------
  u16* word_h = (u16*)alloc((size_t)32768*512*2);        // 33.55 MB, whole run
  char* R     = (char*)alloc((size_t)155189248);         // 155.2 MB aliased region
  u16* A_word = (u16*)(R);                               // prep phase (21.0 MB)
  u16* XGword = (u16*)(R + 20971520);                    // word phase (134.2 MB)
  u16* c0     = (u16*)(R);                               // reduce (33.55) - after XGword dead
  u16* h1     = (u16*)(R + 33554432);                    // 16.8
  u16* h2     = (u16*)(R + 50331648);                    // 16.8
  float* c_big= (float*)(R + 67108864);                  // 33.55
  u16* fb     = (u16*)(R + 100663296);                   // 33.55
  u16* red    = (u16*)(R + 134217728);                   // 16.8 (alive through con)
  u16* XG_con = (u16*)(R);                               // con phase (67.1) - reduce bufs dead
  // weights / small (persistent)
  u16* wWih = (u16*)alloc((size_t)2048*320*2);
  u16* wWhh = (u16*)alloc((size_t)2048*512*2);
  u16* tWih = (u16*)alloc((size_t)2048*32*2);
  u16* tWhh = (u16*)alloc((size_t)2048*512*2);
  u16* cWihp = (u16*)alloc((size_t)2048*512*2);
  u16* cWhhp = (u16*)alloc((size_t)2048*512*2);
  u16* fWcat = (u16*)alloc((size_t)2048*1024*2);
  u16* bWcat = (u16*)alloc((size_t)2048*1024*2);
  u16* fWih  = (u16*)alloc((size_t)2048*512*2);
  u16* bWih  = (u16*)alloc((size_t)2048*512*2);
  u16* w2cWb = (u16*)alloc((size_t)512*512*2);
  u16* redWb = (u16*)alloc((size_t)512*1024*2);
  u16* A80   = (u16*)alloc((size_t)128*512*2);
  u16* Atr   = (u16*)alloc((size_t)128*32*2);
  u16* tbltr = (u16*)alloc((size_t)128*2048*2);
  u16* tbl0  = (u16*)alloc((size_t)128*2048*2);
  float* b_word = (float*)alloc(2048*4);
  float* b_tr   = (float*)alloc(2048*4);
  float* b_con  = (float*)alloc(2048*4);
  float* b_fwd  = (float*)alloc(2048*4);
  float* b_bwd  = (float*)alloc(2048*4);
  float* c_word = (float*)alloc((size_t)128*512*4);
  float* c_tr   = (float*)alloc((size_t)128*512*4);
  float* c_con  = (float*)alloc((size_t)128*512*4);
  u16* trh1 = (u16*)alloc((size_t)128*512*2);
  u16* trh2 = (u16*)alloc((size_t)128*512*2);
  u16* ch1  = (u16*)alloc((size_t)128*512*2);
  u16* ch2  = (u16*)alloc((size_t)128*512*2);
  u32* flags = (u32*)alloc((size_t)4*64*32*4);   // 4 groups x 64 flags x 32-u32 pad

  // ---- init ----
  k_zero<<<32,256,0,stream>>>(flags, 4*64*32);

  // ---- preps ----
  k_perm_w<<<2048,256,0,stream>>>(word_Wih, wWih, 320, 320, 320, 0);
  k_perm_w<<<2048,256,0,stream>>>(word_Whh, wWhh, 512, 512, 512, 0);
  k_perm_w<<<2048,256,0,stream>>>(tr_Wih,   tWih, 20,  32,  32,  0);
  k_perm_w<<<2048,256,0,stream>>>(tr_Whh,   tWhh, 512, 512, 512, 0);
  k_perm_w<<<2048,256,0,stream>>>(con_Wih,  cWihp, 512, 512, 512, 0);
  k_perm_w<<<2048,256,0,stream>>>(con_Whh,  cWhhp, 512, 512, 512, 0);
  k_perm_w<<<2048,256,0,stream>>>(fwd_Whh,  fWcat, 512, 512, 1024, 0);
  k_perm_w<<<2048,256,0,stream>>>(fwd_Wih,  fWcat, 512, 512, 1024, 512);
  k_perm_w<<<2048,256,0,stream>>>(bwd_Whh,  bWcat, 512, 512, 1024, 0);
  k_perm_w<<<2048,256,0,stream>>>(bwd_Wih,  bWcat, 512, 512, 1024, 512);
  k_perm_w<<<2048,256,0,stream>>>(fwd_Wih,  fWih, 512, 512, 512, 0);
  k_perm_w<<<2048,256,0,stream>>>(bwd_Wih,  bWih, 512, 512, 512, 0);
  k_perm_b<<<8,256,0,stream>>>(word_b, b_word);
  k_perm_b<<<8,256,0,stream>>>(tr_b,   b_tr);
  k_perm_b<<<8,256,0,stream>>>(con_b,  b_con);
  k_perm_b<<<8,256,0,stream>>>(fwd_b,  b_fwd);
  k_perm_b<<<8,256,0,stream>>>(bwd_b,  b_bwd);
  k_cvt<<<1024,256,0,stream>>>(w2c_W, w2cWb, 512*512);
  k_cvt<<<2048,256,0,stream>>>(red_W, redWb, 512*1024);
  k_pad2d<<<128,256,0,stream>>>(const_emb, A80, 80, 512, 512);
  k_pad2d<<<128,256,0,stream>>>(tr_emb,    Atr, 100, 20, 32);
  k_gather_word<<<32768,256,0,stream>>>(word_idx, tag_idx, emb, tag_emb, A_word);

  // ---- XG tables ----
  k_gemm<<<dim3(256,16),256,0,stream>>>(A_word, wWih, XGword, b_word, 320, 2048, 0);
  k_gemm<<<dim3(1,16),256,0,stream>>>(Atr, tWih, tbltr, b_tr, 32, 2048, 0);

  // ---- step 0 for word and transition ----
  k_gate0<<<256,256,0,stream>>>(XGword, 0, 1, nullptr, 0, c_word, word_h, 512, 0, 128);
  k_gate0<<<256,256,0,stream>>>(tbltr, 2, 0, tr_idx, 512, c_tr, trh1, 512, 0, 128);

  // ---- launch 1: word(1..255) || transition(1..255) ----
  SeqJob jw{ word_h, nullptr, nullptr, XGword, nullptr, c_word, wWhh, flags + 0*2048, 1, 256, 0, 0 };
  SeqJob jt1{ nullptr, trh1, trh2, tbltr, tr_idx, c_tr, tWhh, flags + 1*2048, 1, 256, 1, 1 };
  k_seq2<<<128,256,0,stream>>>(jw, jt1);

  // ---- w2c: c0 = word_h @ w2c_W^T + b ----
  k_gemm<<<dim3(256,4),256,0,stream>>>(word_h, w2cWb, c0, w2c_b, 512, 512, 0);

  // ---- fwd reduce ----
  k_gemm<<<dim3(1,16),256,0,stream>>>(A80, fWih, tbl0, b_fwd, 512, 2048, 0);
  k_gate0<<<32768,256,0,stream>>>(tbl0, 2, 0, lab_idx, 1, c_big, h1, 512, 0, 16384);
  k_lstm_cat<<<dim3(128,16),256,0,stream>>>(h1, c0, fWcat, b_fwd, nullptr, 1, 0, 0, c_big, h2, 512, 0);
  k_lstm_cat<<<dim3(128,16),256,0,stream>>>(h2, c0, fWcat, b_fwd, nullptr, 1, 1, 0, c_big, fb, 1024, 0);
  // ---- bwd reduce ----
  k_gemm<<<dim3(1,16),256,0,stream>>>(A80, bWih, tbl0, b_bwd, 512, 2048, 0);
  k_gate0<<<32768,256,0,stream>>>(tbl0, 2, 0, lab_idx, 1, c_big, h1, 512, 0, 16384);
  k_lstm_cat<<<dim3(128,16),256,0,stream>>>(h1, c0, bWcat, b_bwd, nullptr, 1, 1, 0, c_big, h2, 512, 0);
  k_lstm_cat<<<dim3(128,16),256,0,stream>>>(h2, c0, bWcat, b_bwd, nullptr, 1, 0, 0, c_big, fb, 1024, 512);

  // ---- red = tanh([fh|bh] @ red_W^T + b) ----
  k_gemm<<<dim3(128,4),256,0,stream>>>(fb, redWb, red, red_b, 1024, 512, 1);

  // ---- XG_con = red @ con_Wih^T + b_con (reduce buffers dead) ----
  k_gemm<<<dim3(128,16),256,0,stream>>>(red, cWihp, XG_con, b_con, 512, 2048, 0);

  // ---- con step 0 ----
  k_gate0<<<256,256,0,stream>>>(XG_con, 0, 128, nullptr, 0, c_con, ch1, 512, 0, 128);

  // ---- launch 2: con(1..127) || transition(256..511) ----
  SeqJob jc{ nullptr, ch1, ch2, XG_con, nullptr, c_con, cWhhp, flags + 2*2048, 1, 128, 2, 0 };
  SeqJob jt2{ nullptr, trh1, trh2, tbltr, tr_idx, c_tr, tWhh, flags + 3*2048, 256, 512, 1, 0 };
  k_seq2<<<128,256,0,stream>>>(jc, jt2);

  // ---- output ----
  k_out<<<3200,256,0,stream>>>(word_h + (size_t)255*128*512, trh2, ch2,
                               out_W, out_b, (float*)d_out);
}

// Round 8
// 6399.355 us; speedup vs baseline: 8.4775x; 2.2730x over previous
//
#include <hip/hip_runtime.h>

typedef unsigned short u16;
typedef unsigned int u32;
typedef unsigned long long u64;
typedef __attribute__((ext_vector_type(8))) short short8;
typedef __attribute__((ext_vector_type(4))) float f32x4;

namespace {
constexpr int kS  = 256;
constexpr int kT  = 512;
constexpr int kNT = 100;
constexpr int LDST = 40;   // LDS row stride (bf16) for 32-wide K chunks (cat/gemm kernels)
}

__device__ __forceinline__ float bf(u16 v){ return __uint_as_float(((u32)v)<<16); }
__device__ __forceinline__ u16 f2bf(float f){
  u32 u = __float_as_uint(f);
  return (u16)((u + 0x7fffu + ((u>>16)&1u)) >> 16);
}
__device__ __forceinline__ float sigm(float x){ return 1.f/(1.f+__expf(-x)); }
__device__ __forceinline__ float tanha(float x){ return 2.f/(1.f+__expf(-2.f*x)) - 1.f; }
__device__ __forceinline__ float wred(float v){
  #pragma unroll
  for (int off=32; off>0; off>>=1) v += __shfl_xor(v, off, 64);
  return v;
}

// coherence-point (MALL) accesses: relaxed SYSTEM scope -> sc0 sc1, no wbl2/inv
__device__ __forceinline__ u64 ld_sys_u64(const void* p){
  return __hip_atomic_load((const u64*)p, __ATOMIC_RELAXED, __HIP_MEMORY_SCOPE_SYSTEM);
}
__device__ __forceinline__ void st_sys_u32(void* p, u32 v){
  __hip_atomic_store((u32*)p, v, __ATOMIC_RELAXED, __HIP_MEMORY_SCOPE_SYSTEM);
}
__device__ __forceinline__ u32 ld_sys_u32(const void* p){
  return __hip_atomic_load((const u32*)p, __ATOMIC_RELAXED, __HIP_MEMORY_SCOPE_SYSTEM);
}

__global__ void k_zero(u32* p, int n){
  const int i = blockIdx.x*256 + threadIdx.x;
  if (i < n) p[i] = 0;
}

// ================= uniform persistent step kernel =================
// Each block owns 32 gate-cols (8 h-cols); Whh tile resident in LDS; c in LDS.
// All shared h traffic goes through the device coherence point (sc0 sc1) —
// no cache-maintenance (wbl2/inv) anywhere in the step loop.
struct SeqJob {
  u16* hseq; u16* hb0; u16* hb1;
  const u16* xg; const int* idx;
  float* c_io;
  const u16* Bw;     // permuted Whh [2048][512]
  u32* flags;        // 64 flags, 32-u32 padded
  int s_begin, s_end, mode, c_store;
};

__global__ __launch_bounds__(256,1) void k_seq2(SeqJob jA, SeqJob jB)
{
  __shared__ u16 Bs[32*520];          // 33.3 KB resident weight tile
  __shared__ float c_lds[128*9];      // block-private c columns
  __shared__ float sc[4*4*16*20];     // wave-private epilogue scratch
  const SeqJob j = (blockIdx.x < 64) ? jA : jB;
  const int gb = blockIdx.x & 63;
  const int tid = threadIdx.x;
  const int ln = tid & 63, w = tid >> 6, wm = w * 32;
  const int fr = ln & 15, koff = (ln >> 4) * 8;
  const int n0 = gb * 32, jh0 = gb * 8;

  for (int e = tid; e < 2048; e += 256) {
    const int cl = e >> 6, kb = (e & 63) * 8;
    *(uint4*)&Bs[cl*520 + kb] = *(const uint4*)&j.Bw[(size_t)(n0+cl)*512 + kb];
  }
  for (int e = tid; e < 1024; e += 256) {
    const int m = e >> 3, jj = e & 7;
    c_lds[m*9 + jj] = j.c_io[(size_t)m*512 + jh0 + jj];
  }
  __syncthreads();

  const size_t aoff0 = (size_t)(wm + fr)*512 + koff;
  const size_t aoff1 = (size_t)(wm + 16 + fr)*512 + koff;
  const int cr = (ln>>4)*4, cc = ln&15;
  const int trow = ln>>2, pp = ln&3, ntp = pp>>1, cp = pp&1;
  const f32x4 z4 = {0.f,0.f,0.f,0.f};

  for (int s = j.s_begin; s < j.s_end; ++s) {
    const u16* Ab; u16* hout;
    if (j.mode == 0) { Ab = j.hseq + (size_t)(s-1)*65536; hout = j.hseq + (size_t)s*65536; }
    else { Ab = ((s-1)&1) ? j.hb1 : j.hb0; hout = (s&1) ? j.hb1 : j.hb0; }
    const u16* xgs = (j.mode == 0) ? (j.xg + (size_t)s*262144) : j.xg;

    // preload the whole step's A fragments from the coherence point
    u64 aq0[16][2], aq1[16][2];
    #pragma unroll
    for (int kt = 0; kt < 16; ++kt) {
      aq0[kt][0] = ld_sys_u64(&Ab[aoff0 + kt*32]);
      aq0[kt][1] = ld_sys_u64(&Ab[aoff0 + kt*32 + 4]);
      aq1[kt][0] = ld_sys_u64(&Ab[aoff1 + kt*32]);
      aq1[kt][1] = ld_sys_u64(&Ab[aoff1 + kt*32 + 4]);
    }
    f32x4 acc[2][2] = {{z4,z4},{z4,z4}};
    #pragma unroll
    for (int kt = 0; kt < 16; ++kt) {
      union { u64 q[2]; short8 v; } ua, ub;
      ua.q[0] = aq0[kt][0]; ua.q[1] = aq0[kt][1];
      ub.q[0] = aq1[kt][0]; ub.q[1] = aq1[kt][1];
      const short8 b0 = *(const short8*)&Bs[fr*520 + kt*32 + koff];
      const short8 b1 = *(const short8*)&Bs[(16+fr)*520 + kt*32 + koff];
      acc[0][0] = __builtin_amdgcn_mfma_f32_16x16x32_bf16(ua.v, b0, acc[0][0], 0,0,0);
      acc[0][1] = __builtin_amdgcn_mfma_f32_16x16x32_bf16(ua.v, b1, acc[0][1], 0,0,0);
      acc[1][0] = __builtin_amdgcn_mfma_f32_16x16x32_bf16(ub.v, b0, acc[1][0], 0,0,0);
      acc[1][1] = __builtin_amdgcn_mfma_f32_16x16x32_bf16(ub.v, b1, acc[1][1], 0,0,0);
    }

    // epilogue: wave-private transpose via LDS
    #pragma unroll
    for (int mt=0; mt<2; ++mt)
      #pragma unroll
      for (int nt=0; nt<2; ++nt) {
        float* scb = &sc[(size_t)(w*4 + mt*2 + nt)*320];
        #pragma unroll
        for (int ri=0; ri<4; ++ri) scb[(cr+ri)*20 + cc] = acc[mt][nt][ri];
      }
    // gates: each lane produces 2 adjacent h cols -> one packed u32 store
    #pragma unroll
    for (int mt=0; mt<2; ++mt) {
      const int m = wm + mt*16 + trow;
      const float* scb = &sc[(size_t)(w*4+mt*2+ntp)*320 + trow*20 + cp*8];
      const float4 zlo = *(const float4*)&scb[0];
      const float4 zhi = *(const float4*)&scb[4];
      long xr;
      if (j.mode == 0) xr = m;
      else if (j.mode == 1) xr = j.idx[(size_t)m*512 + s];
      else xr = (long)m*128 + s;
      union { uint4 u4; u16 h[8]; } xq;
      xq.u4 = *(const uint4*)&xgs[(size_t)xr*2048 + n0 + ntp*16 + cp*8];
      const int cj = m*9 + ntp*4 + cp*2;
      float h0, h1;
      {
        const float i_ = sigm(zlo.x + bf(xq.h[0]));
        const float f_ = sigm(zlo.y + bf(xq.h[1]));
        const float g_ = tanha(zlo.z + bf(xq.h[2]));
        const float o_ = sigm(zlo.w + bf(xq.h[3]));
        const float cn = f_*c_lds[cj] + i_*g_;
        c_lds[cj] = cn;
        h0 = o_*tanha(cn);
      }
      {
        const float i_ = sigm(zhi.x + bf(xq.h[4]));
        const float f_ = sigm(zhi.y + bf(xq.h[5]));
        const float g_ = tanha(zhi.z + bf(xq.h[6]));
        const float o_ = sigm(zhi.w + bf(xq.h[7]));
        const float cn = f_*c_lds[cj+1] + i_*g_;
        c_lds[cj+1] = cn;
        h1 = o_*tanha(cn);
      }
      const u32 pk = (u32)f2bf(h0) | ((u32)f2bf(h1) << 16);
      st_sys_u32(&hout[(size_t)m*512 + jh0 + ntp*4 + cp*2], pk);
    }

    // ---- fence-free sync: drain to coherence point, signal, poll ----
    __builtin_amdgcn_s_waitcnt(0);
    __syncthreads();
    if (tid == 0)
      st_sys_u32(j.flags + (gb << 5), (u32)s);
    if (s + 1 < j.s_end) {
      if (tid < 64) {
        while (true) {
          u32 f = ld_sys_u32(j.flags + (tid << 5));
          if (__all((int)(f >= (u32)s))) break;
          __builtin_amdgcn_s_sleep(2);
        }
      }
      __syncthreads();
    }
  }
  if (j.c_store) {
    __syncthreads();
    for (int e = tid; e < 1024; e += 256) {
      const int m = e >> 3, jj = e & 7;
      j.c_io[(size_t)m*512 + jh0 + jj] = c_lds[m*9 + jj];
    }
  }
}

// ---------------- shared MFMA K-loop core (linear A): 128x128 C-tile, BK=32 ----------------
__device__ __forceinline__ void gemm_core(
    const u16* __restrict__ A, const u16* __restrict__ B, int K,
    int m0, int n0, u16* As, u16* Bs, f32x4 acc[4][4], int tid)
{
  const int lane = tid & 63;
  const int w = tid >> 6;
  const int wm = (w & 1) * 64, wn = (w >> 1) * 64;
  const int fr = lane & 15;
  const int fq = (lane >> 4) * 8;
  for (int k0 = 0; k0 < K; k0 += 32) {
    __syncthreads();
    #pragma unroll
    for (int it = 0; it < 2; ++it) {
      const int l = tid + it * 256;
      const int r = l >> 2, kq = (l & 3) * 8;
      *(uint4*)&As[r * LDST + kq] = *(const uint4*)&A[(size_t)(m0 + r) * K + k0 + kq];
      *(uint4*)&Bs[r * LDST + kq] = *(const uint4*)&B[(size_t)(n0 + r) * K + k0 + kq];
    }
    __syncthreads();
    short8 af[4], bfr[4];
    #pragma unroll
    for (int t = 0; t < 4; ++t) {
      af[t]  = *(const short8*)&As[(wm + t * 16 + fr) * LDST + fq];
      bfr[t] = *(const short8*)&Bs[(wn + t * 16 + fr) * LDST + fq];
    }
    #pragma unroll
    for (int mt = 0; mt < 4; ++mt)
      #pragma unroll
      for (int nt = 0; nt < 4; ++nt)
        acc[mt][nt] = __builtin_amdgcn_mfma_f32_16x16x32_bf16(af[mt], bfr[nt], acc[mt][nt], 0, 0, 0);
  }
}

// ---------------- plain GEMM: C = A @ B^T (+bias) (opt tanh), C bf16 ----------------
__global__ __launch_bounds__(256) void k_gemm(
    const u16* __restrict__ A, const u16* __restrict__ B, u16* __restrict__ C,
    const float* __restrict__ bias, int K, int N, int tanh_flag)
{
  __shared__ u16 As[128 * LDST];
  __shared__ u16 Bs[128 * LDST];
  const int tid = threadIdx.x;
  const int m0 = blockIdx.x * 128, n0 = blockIdx.y * 128;
  f32x4 acc[4][4];
  const f32x4 z4 = {0.f, 0.f, 0.f, 0.f};
  #pragma unroll
  for (int mt = 0; mt < 4; ++mt)
    #pragma unroll
    for (int nt = 0; nt < 4; ++nt) acc[mt][nt] = z4;

  gemm_core(A, B, K, m0, n0, As, Bs, acc, tid);

  const int lane = tid & 63;
  const int w = tid >> 6;
  const int wm = (w & 1) * 64, wn = (w >> 1) * 64;
  const int cr = (lane >> 4) * 4, cc = lane & 15;
  #pragma unroll
  for (int mt = 0; mt < 4; ++mt)
    #pragma unroll
    for (int nt = 0; nt < 4; ++nt)
      #pragma unroll
      for (int ri = 0; ri < 4; ++ri) {
        const int row = m0 + wm + mt * 16 + cr + ri;
        const int col = n0 + wn + nt * 16 + cc;
        float v = acc[mt][nt][ri];
        if (bias) v += bias[col];
        if (tanh_flag) v = tanha(v);
        C[(size_t)row * N + col] = f2bf(v);
      }
}

// ---------------- fused concat-K step (one step, many rows): reduce steps 2/3 ----------------
__global__ __launch_bounds__(256) void k_lstm_cat(
    const u16* __restrict__ H, const u16* __restrict__ X,
    const u16* __restrict__ B, const float* __restrict__ bias,
    const int* __restrict__ idx, int cmode, int p0, int first,
    float* __restrict__ c_st, u16* __restrict__ h_out, int h_stride, int h_coloff)
{
  __shared__ u16 As[128 * LDST];
  __shared__ u16 Bs[128 * LDST];
  __shared__ float zb[64 * 128];
  const int tid = threadIdx.x;
  const int m0 = blockIdx.x * 128, n0 = blockIdx.y * 128;
  const int lane = tid & 63;
  const int w = tid >> 6;
  const int wm = (w & 1) * 64, wn = (w >> 1) * 64;
  const int fr = lane & 15, fq = (lane >> 4) * 8;
  f32x4 acc[4][4];
  const f32x4 z4 = {0.f, 0.f, 0.f, 0.f};
  #pragma unroll
  for (int mt = 0; mt < 4; ++mt)
    #pragma unroll
    for (int nt = 0; nt < 4; ++nt) acc[mt][nt] = z4;

  for (int k0 = first ? 512 : 0; k0 < 1024; k0 += 32) {
    __syncthreads();
    #pragma unroll
    for (int it = 0; it < 2; ++it) {
      const int l = tid + it * 256;
      const int r = l >> 2, kq = (l & 3) * 8;
      const int m = m0 + r;
      const u16* src;
      if (k0 < 512) {
        src = H + (size_t)m * 512 + k0 + kq;
      } else {
        long xr;
        if (cmode == 1)      xr = (long)(2 * (m & 127) + p0) * 128 + (m >> 7);
        else if (cmode == 2) xr = (long)idx[m];
        else                 xr = (long)m * 128 + p0;
        src = X + (size_t)xr * 512 + (k0 - 512) + kq;
      }
      *(uint4*)&As[r * LDST + kq] = *(const uint4*)src;
      *(uint4*)&Bs[r * LDST + kq] = *(const uint4*)&B[(size_t)(n0 + r) * 1024 + k0 + kq];
    }
    __syncthreads();
    short8 af[4], bfr[4];
    #pragma unroll
    for (int t = 0; t < 4; ++t) {
      af[t]  = *(const short8*)&As[(wm + t * 16 + fr) * LDST + fq];
      bfr[t] = *(const short8*)&Bs[(wn + t * 16 + fr) * LDST + fq];
    }
    #pragma unroll
    for (int mt = 0; mt < 4; ++mt)
      #pragma unroll
      for (int nt = 0; nt < 4; ++nt)
        acc[mt][nt] = __builtin_amdgcn_mfma_f32_16x16x32_bf16(af[mt], bfr[nt], acc[mt][nt], 0, 0, 0);
  }

  const int cr = (lane >> 4) * 4, cc = lane & 15;
  #pragma unroll
  for (int half = 0; half < 2; ++half) {
    __syncthreads();
    if (wm == half * 64) {
      #pragma unroll
      for (int mt = 0; mt < 4; ++mt)
        #pragma unroll
        for (int nt = 0; nt < 4; ++nt)
          #pragma unroll
          for (int ri = 0; ri < 4; ++ri)
            zb[(mt * 16 + cr + ri) * 128 + wn + nt * 16 + cc] = acc[mt][nt][ri];
    }
    __syncthreads();
    for (int c = tid; c < 2048; c += 256) {
      const int rl = c >> 5;
      const int q  = c & 31;
      const int m  = m0 + half * 64 + rl;
      const int jh = (n0 >> 2) + q;
      const float4 bv = *(const float4*)&bias[n0 + q * 4];
      const float4 zv = *(const float4*)&zb[rl * 128 + q * 4];
      const float i_ = sigm(zv.x + bv.x);
      const float f_ = sigm(zv.y + bv.y);
      const float g_ = tanha(zv.z + bv.z);
      const float o_ = sigm(zv.w + bv.w);
      const size_t ci = (size_t)m * 512 + jh;
      const float cold = first ? 0.f : c_st[ci];
      const float cn = f_ * cold + i_ * g_;
      c_st[ci] = cn;
      h_out[(size_t)m * h_stride + h_coloff + jh] = f2bf(o_ * tanha(cn));
    }
  }
}

// ---------------- first LSTM step from XG table (no h) ----------------
__global__ __launch_bounds__(256) void k_gate0(
    const u16* __restrict__ xg, int xg_mode, int p0,
    const int* __restrict__ idx, int istride,
    float* __restrict__ c_st, u16* __restrict__ h_out, int h_stride, int h_coloff, int M)
{
  const int id = blockIdx.x * 256 + threadIdx.x;
  if (id >= M * 512) return;
  const int m = id >> 9, jh = id & 511;
  long xr;
  if (xg_mode == 0) xr = (long)m * p0;
  else              xr = (long)idx[(size_t)m * istride];
  const ushort4 xq = *(const ushort4*)&xg[(size_t)xr * 2048 + jh * 4];
  const float i_ = sigm(bf(xq.x));
  const float g_ = tanha(bf(xq.z));
  const float o_ = sigm(bf(xq.w));
  const float cn = i_ * g_;
  c_st[(size_t)m * 512 + jh] = cn;
  h_out[(size_t)m * h_stride + h_coloff + jh] = f2bf(o_ * tanha(cn));
}

// ---------------- preps ----------------
__global__ void k_perm_w(const float* __restrict__ in, u16* __restrict__ out,
                         int Ksrc, int Kfill, int Ktot, int coff)
{
  const int rp = blockIdx.x;             // 0..2047
  const int g = rp & 3, jh = rp >> 2;
  const float* src = in + (size_t)(g * 512 + jh) * Ksrc;
  for (int k = threadIdx.x; k < Kfill; k += 256)
    out[(size_t)rp * Ktot + coff + k] = f2bf(k < Ksrc ? src[k] : 0.f);
}
__global__ void k_perm_b(const float* __restrict__ in, float* __restrict__ out)
{
  const int rp = blockIdx.x * 256 + threadIdx.x;
  out[rp] = in[(rp & 3) * 512 + (rp >> 2)];
}
__global__ void k_cvt(const float* __restrict__ in, u16* __restrict__ out, int n)
{
  const int i = blockIdx.x * 256 + threadIdx.x;
  if (i < n) out[i] = f2bf(in[i]);
}
__global__ void k_pad2d(const float* __restrict__ in, u16* __restrict__ out,
                        int Rin, int Kin, int Kout)
{
  const int r = blockIdx.x;
  for (int k = threadIdx.x; k < Kout; k += 256)
    out[(size_t)r * Kout + k] = f2bf((r < Rin && k < Kin) ? in[(size_t)r * Kin + k] : 0.f);
}
__global__ void k_gather_word(const int* __restrict__ widx, const int* __restrict__ tidx,
                              const float* __restrict__ emb, const float* __restrict__ temb,
                              u16* __restrict__ Aw)
{
  const int row = blockIdx.x;            // 0..32767 = s*128+b
  const int s = row >> 7, b = row & 127;
  const int wi = widx[b * kS + s];
  const int ti = tidx[b * kS + s];
  for (int t = threadIdx.x; t < 320; t += 256)
    Aw[(size_t)row * 320 + t] = f2bf(t < 300 ? emb[(size_t)wi * 300 + t] : temb[ti * 20 + t - 300]);
}

// ---------------- out = [word_h_last | tr_h | con_h] @ W^T + b ----------------
__global__ __launch_bounds__(256) void k_out(
    const u16* __restrict__ wh, const u16* __restrict__ trh, const u16* __restrict__ conh,
    const float* __restrict__ W, const float* __restrict__ bias, float* __restrict__ out)
{
  const int wid = blockIdx.x * 4 + (threadIdx.x >> 6);
  const int lane = threadIdx.x & 63;
  const int b = wid / kNT;
  const int t = wid - b * kNT;
  const u16* s0 = wh + (size_t)b * 512;
  const u16* s1 = trh + (size_t)b * 512;
  const u16* s2 = conh + (size_t)b * 512;
  const float* wr = W + (size_t)t * 1536;
  float acc = 0.f;
  #pragma unroll
  for (int i = 0; i < 8; ++i) acc += bf(s0[i * 64 + lane]) * wr[i * 64 + lane];
  #pragma unroll
  for (int i = 0; i < 8; ++i) acc += bf(s1[i * 64 + lane]) * wr[512 + i * 64 + lane];
  #pragma unroll
  for (int i = 0; i < 8; ++i) acc += bf(s2[i * 64 + lane]) * wr[1024 + i * 64 + lane];
  acc = wred(acc);
  if (lane == 0) out[(size_t)b * kNT + t] = acc + bias[t];
}

extern "C" void kernel_launch(void* const* d_in, const int* in_sizes, int n_in,
                              void* d_out, int out_size, void* d_ws, size_t ws_size,
                              hipStream_t stream)
{
  (void)in_sizes; (void)n_in; (void)out_size; (void)ws_size;
  const int* word_idx = (const int*)d_in[0];
  const int* tag_idx  = (const int*)d_in[1];
  const int* tr_idx   = (const int*)d_in[2];
  const int* lab_idx  = (const int*)d_in[3];
  const float* emb       = (const float*)d_in[4];
  const float* tag_emb   = (const float*)d_in[5];
  const float* tr_emb    = (const float*)d_in[6];
  const float* const_emb = (const float*)d_in[7];
  const float* word_Wih = (const float*)d_in[8];
  const float* word_Whh = (const float*)d_in[9];
  const float* word_b   = (const float*)d_in[10];
  const float* tr_Wih = (const float*)d_in[11];
  const float* tr_Whh = (const float*)d_in[12];
  const float* tr_b   = (const float*)d_in[13];
  const float* con_Wih = (const float*)d_in[14];
  const float* con_Whh = (const float*)d_in[15];
  const float* con_b   = (const float*)d_in[16];
  const float* fwd_Wih = (const float*)d_in[17];
  const float* fwd_Whh = (const float*)d_in[18];
  const float* fwd_b   = (const float*)d_in[19];
  const float* bwd_Wih = (const float*)d_in[20];
  const float* bwd_Whh = (const float*)d_in[21];
  const float* bwd_b   = (const float*)d_in[22];
  const float* w2c_W = (const float*)d_in[23];
  const float* w2c_b = (const float*)d_in[24];
  const float* red_W = (const float*)d_in[25];
  const float* red_b = (const float*)d_in[26];
  const float* out_W = (const float*)d_in[27];
  const float* out_b = (const float*)d_in[28];

  char* p = (char*)d_ws;
  auto alloc = [&](size_t bytes)->void* {
    void* r = (void*)p; p += (bytes + 255) & ~(size_t)255; return r;
  };
  // -------- arena (~215 MB; phase-aliased big region) --------
  u16* word_h = (u16*)alloc((size_t)32768*512*2);        // 33.55 MB, whole run
  char* R     = (char*)alloc((size_t)155189248);         // 155.2 MB aliased region
  u16* A_word = (u16*)(R);                               // prep phase (21.0 MB)
  u16* XGword = (u16*)(R + 20971520);                    // word phase (134.2 MB)
  u16* c0     = (u16*)(R);                               // reduce (33.55) - after XGword dead
  u16* h1     = (u16*)(R + 33554432);                    // 16.8
  u16* h2     = (u16*)(R + 50331648);                    // 16.8
  float* c_big= (float*)(R + 67108864);                  // 33.55
  u16* fb     = (u16*)(R + 100663296);                   // 33.55
  u16* red    = (u16*)(R + 134217728);                   // 16.8 (alive through con)
  u16* XG_con = (u16*)(R);                               // con phase (67.1) - reduce bufs dead
  // weights / small (persistent)
  u16* wWih = (u16*)alloc((size_t)2048*320*2);
  u16* wWhh = (u16*)alloc((size_t)2048*512*2);
  u16* tWih = (u16*)alloc((size_t)2048*32*2);
  u16* tWhh = (u16*)alloc((size_t)2048*512*2);
  u16* cWihp = (u16*)alloc((size_t)2048*512*2);
  u16* cWhhp = (u16*)alloc((size_t)2048*512*2);
  u16* fWcat = (u16*)alloc((size_t)2048*1024*2);
  u16* bWcat = (u16*)alloc((size_t)2048*1024*2);
  u16* fWih  = (u16*)alloc((size_t)2048*512*2);
  u16* bWih  = (u16*)alloc((size_t)2048*512*2);
  u16* w2cWb = (u16*)alloc((size_t)512*512*2);
  u16* redWb = (u16*)alloc((size_t)512*1024*2);
  u16* A80   = (u16*)alloc((size_t)128*512*2);
  u16* Atr   = (u16*)alloc((size_t)128*32*2);
  u16* tbltr = (u16*)alloc((size_t)128*2048*2);
  u16* tbl0  = (u16*)alloc((size_t)128*2048*2);
  float* b_word = (float*)alloc(2048*4);
  float* b_tr   = (float*)alloc(2048*4);
  float* b_con  = (float*)alloc(2048*4);
  float* b_fwd  = (float*)alloc(2048*4);
  float* b_bwd  = (float*)alloc(2048*4);
  float* c_word = (float*)alloc((size_t)128*512*4);
  float* c_tr   = (float*)alloc((size_t)128*512*4);
  float* c_con  = (float*)alloc((size_t)128*512*4);
  u16* trh1 = (u16*)alloc((size_t)128*512*2);
  u16* trh2 = (u16*)alloc((size_t)128*512*2);
  u16* ch1  = (u16*)alloc((size_t)128*512*2);
  u16* ch2  = (u16*)alloc((size_t)128*512*2);
  u32* flags = (u32*)alloc((size_t)4*64*32*4);   // 4 groups x 64 flags x 32-u32 pad

  // ---- init ----
  k_zero<<<32,256,0,stream>>>(flags, 4*64*32);

  // ---- preps ----
  k_perm_w<<<2048,256,0,stream>>>(word_Wih, wWih, 320, 320, 320, 0);
  k_perm_w<<<2048,256,0,stream>>>(word_Whh, wWhh, 512, 512, 512, 0);
  k_perm_w<<<2048,256,0,stream>>>(tr_Wih,   tWih, 20,  32,  32,  0);
  k_perm_w<<<2048,256,0,stream>>>(tr_Whh,   tWhh, 512, 512, 512, 0);
  k_perm_w<<<2048,256,0,stream>>>(con_Wih,  cWihp, 512, 512, 512, 0);
  k_perm_w<<<2048,256,0,stream>>>(con_Whh,  cWhhp, 512, 512, 512, 0);
  k_perm_w<<<2048,256,0,stream>>>(fwd_Whh,  fWcat, 512, 512, 1024, 0);
  k_perm_w<<<2048,256,0,stream>>>(fwd_Wih,  fWcat, 512, 512, 1024, 512);
  k_perm_w<<<2048,256,0,stream>>>(bwd_Whh,  bWcat, 512, 512, 1024, 0);
  k_perm_w<<<2048,256,0,stream>>>(bwd_Wih,  bWcat, 512, 512, 1024, 512);
  k_perm_w<<<2048,256,0,stream>>>(fwd_Wih,  fWih, 512, 512, 512, 0);
  k_perm_w<<<2048,256,0,stream>>>(bwd_Wih,  bWih, 512, 512, 512, 0);
  k_perm_b<<<8,256,0,stream>>>(word_b, b_word);
  k_perm_b<<<8,256,0,stream>>>(tr_b,   b_tr);
  k_perm_b<<<8,256,0,stream>>>(con_b,  b_con);
  k_perm_b<<<8,256,0,stream>>>(fwd_b,  b_fwd);
  k_perm_b<<<8,256,0,stream>>>(bwd_b,  b_bwd);
  k_cvt<<<1024,256,0,stream>>>(w2c_W, w2cWb, 512*512);
  k_cvt<<<2048,256,0,stream>>>(red_W, redWb, 512*1024);
  k_pad2d<<<128,256,0,stream>>>(const_emb, A80, 80, 512, 512);
  k_pad2d<<<128,256,0,stream>>>(tr_emb,    Atr, 100, 20, 32);
  k_gather_word<<<32768,256,0,stream>>>(word_idx, tag_idx, emb, tag_emb, A_word);

  // ---- XG tables ----
  k_gemm<<<dim3(256,16),256,0,stream>>>(A_word, wWih, XGword, b_word, 320, 2048, 0);
  k_gemm<<<dim3(1,16),256,0,stream>>>(Atr, tWih, tbltr, b_tr, 32, 2048, 0);

  // ---- step 0 for word and transition ----
  k_gate0<<<256,256,0,stream>>>(XGword, 0, 1, nullptr, 0, c_word, word_h, 512, 0, 128);
  k_gate0<<<256,256,0,stream>>>(tbltr, 2, 0, tr_idx, 512, c_tr, trh1, 512, 0, 128);

  // ---- launch 1: word(1..255) || transition(1..255) ----
  SeqJob jw{ word_h, nullptr, nullptr, XGword, nullptr, c_word, wWhh, flags + 0*2048, 1, 256, 0, 0 };
  SeqJob jt1{ nullptr, trh1, trh2, tbltr, tr_idx, c_tr, tWhh, flags + 1*2048, 1, 256, 1, 1 };
  k_seq2<<<128,256,0,stream>>>(jw, jt1);

  // ---- w2c: c0 = word_h @ w2c_W^T + b ----
  k_gemm<<<dim3(256,4),256,0,stream>>>(word_h, w2cWb, c0, w2c_b, 512, 512, 0);

  // ---- fwd reduce ----
  k_gemm<<<dim3(1,16),256,0,stream>>>(A80, fWih, tbl0, b_fwd, 512, 2048, 0);
  k_gate0<<<32768,256,0,stream>>>(tbl0, 2, 0, lab_idx, 1, c_big, h1, 512, 0, 16384);
  k_lstm_cat<<<dim3(128,16),256,0,stream>>>(h1, c0, fWcat, b_fwd, nullptr, 1, 0, 0, c_big, h2, 512, 0);
  k_lstm_cat<<<dim3(128,16),256,0,stream>>>(h2, c0, fWcat, b_fwd, nullptr, 1, 1, 0, c_big, fb, 1024, 0);
  // ---- bwd reduce ----
  k_gemm<<<dim3(1,16),256,0,stream>>>(A80, bWih, tbl0, b_bwd, 512, 2048, 0);
  k_gate0<<<32768,256,0,stream>>>(tbl0, 2, 0, lab_idx, 1, c_big, h1, 512, 0, 16384);
  k_lstm_cat<<<dim3(128,16),256,0,stream>>>(h1, c0, bWcat, b_bwd, nullptr, 1, 1, 0, c_big, h2, 512, 0);
  k_lstm_cat<<<dim3(128,16),256,0,stream>>>(h2, c0, bWcat, b_bwd, nullptr, 1, 0, 0, c_big, fb, 1024, 512);

  // ---- red = tanh([fh|bh] @ red_W^T + b) ----
  k_gemm<<<dim3(128,4),256,0,stream>>>(fb, redWb, red, red_b, 1024, 512, 1);

  // ---- XG_con = red @ con_Wih^T + b_con (reduce buffers dead) ----
  k_gemm<<<dim3(128,16),256,0,stream>>>(red, cWihp, XG_con, b_con, 512, 2048, 0);

  // ---- con step 0 ----
  k_gate0<<<256,256,0,stream>>>(XG_con, 0, 128, nullptr, 0, c_con, ch1, 512, 0, 128);

  // ---- launch 2: con(1..127) || transition(256..511) ----
  SeqJob jc{ nullptr, ch1, ch2, XG_con, nullptr, c_con, cWhhp, flags + 2*2048, 1, 128, 2, 0 };
  SeqJob jt2{ nullptr, trh1, trh2, tbltr, tr_idx, c_tr, tWhh, flags + 3*2048, 256, 512, 1, 0 };
  k_seq2<<<128,256,0,stream>>>(jc, jt2);

  // ---- output ----
  k_out<<<3200,256,0,stream>>>(word_h + (size_t)255*128*512, trh2, ch2,
                               out_W, out_b, (float*)d_out);
}